// Round 11
// baseline (9230.861 us; speedup 1.0000x reference)
//
#include <hip/hip_runtime.h>

typedef short bf16x8 __attribute__((ext_vector_type(8)));
typedef float f32x4 __attribute__((ext_vector_type(4)));

#define B_ 256
#define T_ 1024
#define H_ 512
#define E_ 256
#define O_ 256
#define V_ 256

// Prepped operands in device globals: graph-safe, rewritten every launch.
__device__ __align__(16) unsigned short g_P[V_ * H_];     // P = emb@Wx^T + b, bf16 (256 KB)
__device__ __align__(16) unsigned short g_Whf[H_ * H_];   // Wh in MFMA B-frag layout (512 KB)
__device__ __align__(16) unsigned short g_Wdf[O_ * H_];   // Wd in MFMA B-frag layout (256 KB)

// Cross-block h exchange: ROW-MAJOR packed-u32 bf16 pairs (byte image == row-major
// bf16 h matrix). Parity double-buffered.
__device__ __align__(16) unsigned g_ex[2][16][16 * 256];  // 2 x 16 groups x 16 KB
__device__ unsigned g_flag[16][64];                       // flag line per group, 256B pad

__device__ __forceinline__ unsigned short f2bf(float f) {
    union { float f; unsigned int u; } v; v.f = f;
    unsigned int r = v.u + 0x7fffu + ((v.u >> 16) & 1u);   // RNE
    return (unsigned short)(r >> 16);
}
__device__ __forceinline__ float bf2f(unsigned short s) {
    union { unsigned int u; float f; } v; v.u = ((unsigned int)s) << 16;
    return v.f;
}
#define TANH_(v_) (1.f - __fdividef(2.f, __expf((v_) + (v_)) + 1.f))

// ---------------- K1a: P = b + emb @ Wx^T (bf16); zero flags ----------------
__global__ void k_embWx(const float* __restrict__ emb, const float* __restrict__ W,
                        const float* __restrict__ bb) {
    if (blockIdx.x == 0)
        for (int i = threadIdx.x; i < 16 * 64; i += 256) ((unsigned*)g_flag)[i] = 0;
    __shared__ float e[E_];
    int v = blockIdx.x;
    e[threadIdx.x] = emb[(size_t)v * E_ + threadIdx.x];
    __syncthreads();
#pragma unroll
    for (int rep = 0; rep < 2; rep++) {
        int n = threadIdx.x + rep * 256;
        const float4* wr4 = (const float4*)(W + (size_t)n * (E_ + H_));
        float s = bb[n];
        for (int k = 0; k < E_ / 4; k++) {
            float4 wv = wr4[k];
            s += e[4*k] * wv.x + e[4*k+1] * wv.y + e[4*k+2] * wv.z + e[4*k+3] * wv.w;
        }
        g_P[v * H_ + n] = f2bf(s);
    }
}

// ---------------- K1b/K1c: weight -> MFMA B-fragment layout; warm g_ex ----------------
__global__ void k_fragWh(const float* __restrict__ W) {
    int gid = blockIdx.x * blockDim.x + threadIdx.x;
    // pre-touch/zero g_ex (131072 u32 over 32768 threads) — kills first-dispatch
    // cold-page anomaly seen in R10 (34.6 ms first k_rnn)
    {
        unsigned* e = (unsigned*)g_ex;
#pragma unroll
        for (int k = 0; k < 4; k++) e[gid * 4 + k] = 0;
    }
    int l = gid & 63, tile = gid >> 6;
    int kt = tile & 15, nt = tile >> 4;
    int n = nt * 16 + (l & 15), k0 = kt * 32 + (l >> 4) * 8;
    const float* src = W + (size_t)n * (E_ + H_) + E_ + k0;
#pragma unroll
    for (int j = 0; j < 8; j++) g_Whf[(size_t)gid * 8 + j] = f2bf(src[j]);
}
__global__ void k_fragWd(const float* __restrict__ Wd) {
    int gid = blockIdx.x * blockDim.x + threadIdx.x;
    int l = gid & 63, tile = gid >> 6;
    int kt = tile & 15, nt = tile >> 4;
    int n = nt * 16 + (l & 15), k0 = kt * 32 + (l >> 4) * 8;
    const float* src = Wd + (size_t)n * H_ + k0;
#pragma unroll
    for (int j = 0; j < 8; j++) g_Wdf[(size_t)gid * 8 + j] = f2bf(src[j]);
}

// ---------------- K2: recurrence — 4-group pipelined sync (1 L3 chain per 4 steps) ----------------
// 16 blocks = 4 supergroups s x 4 quarters q; block carries groups G_j = s*4+j,
// j=0..3, quarter q of each. Wave owns ntile nt=q*8+w: Wh kt0..11 in 48 VGPRs,
// kt12..15 in 32KB LDS (total reg demand ~115 under the immovable ~128 grant,
// R1-R10). R10 lesson: chain count = T regardless of groups-per-chain; the lever
// is paying the chain's L3 latency (flag flight + gather RT + ack) ONCE for 4
// steps. Iteration: poll 4 flag lines -> batched gather 32 u64 (one RT) -> image
// ds_writes + designated hs write + barrier -> 4x{16 MFMA + tanh(acc+u)} ->
// 16 ex stores -> vmcnt(0) -> barrier -> 4 flag stores. vmcnt(0)-only discipline
// (robust vs divergent hs stores). Parity safety as R9: flag=i implies peer's
// h^(i-1) reads done; h^(i+1) posted only after polling >= i.
__global__ void __launch_bounds__(512) k_rnn(const int* __restrict__ x,
                                             const float* __restrict__ h0,
                                             float* __restrict__ out) {
    __shared__ __align__(16) unsigned short lds_h[4][16 * 512];   // 4 x 16 KB images
    __shared__ __align__(16) unsigned short lds_B[16 * 1024];     // 32 KB: kt 12..15
    const int tid = threadIdx.x;
    const int w = tid >> 6, l = tid & 63;
    const int hi = l >> 4, lo = l & 15;
    const int s = blockIdx.x >> 2, q = blockIdx.x & 3;
    const int nt = q * 8 + w;
    const int n = nt * 16 + lo;
    const int sw = (lo & 7) << 4;               // A-read swizzle

    // pinned Wh B-frags kt 0..11 (48 VGPRs)
    bf16x8 breg[12];
#pragma unroll
    for (int kt = 0; kt < 12; kt++)
        breg[kt] = *(const bf16x8*)(g_Whf + (nt * 16 + kt) * 512 + l * 8);
    // LDS-resident kt 12..15 (wave-private 4 KB regions)
#pragma unroll
    for (int kk = 0; kk < 4; kk++) {
        bf16x8 v = *(const bf16x8*)(g_Whf + (nt * 16 + 12 + kk) * 512 + l * 8);
        *(bf16x8*)((char*)lds_B + (w * 4 + kk) * 1024 + l * 16) = v;
    }

    // stage h^0 images for 4 groups (fp32 -> packed bf16, swizzled)
    {
        const int row = tid >> 5;
        const int cb = (tid & 31) * 32;
        const int gsw = (row & 7) << 4;
#pragma unroll
        for (int j = 0; j < 4; j++) {
            const float* hp = h0 + (size_t)(s * 64 + j * 16 + row) * H_ + (tid & 31) * 16;
            unsigned pk[8];
#pragma unroll
            for (int ii = 0; ii < 8; ii++)
                pk[ii] = (unsigned)f2bf(hp[2 * ii]) | ((unsigned)f2bf(hp[2 * ii + 1]) << 16);
            char* hw = (char*)lds_h[j] + row * 1024;
            *(uint4*)(hw + ((cb)      ^ gsw)) = make_uint4(pk[0], pk[1], pk[2], pk[3]);
            *(uint4*)(hw + ((cb + 16) ^ gsw)) = make_uint4(pk[4], pk[5], pk[6], pk[7]);
        }
    }
    __syncthreads();

    unsigned short* hs = (unsigned short*)out;   // hs bf16 in-place in d_out
    unsigned mp[4][2];                           // packed h rows (0,1),(2,3) per group
#pragma unroll
    for (int j = 0; j < 4; j++) { mp[j][0] = 0; mp[j][1] = 0; }

#pragma unroll 1
    for (unsigned i = 0; i < T_; i++) {
        if (i) {
            // poll: all 4 groups' 4 quarters posted step i (4 lines, 8 u64 loads/round)
            for (;;) {
                unsigned mn = 0xffffffffu;
#pragma unroll
                for (int j = 0; j < 4; j++) {
                    const unsigned long long* fq = (const unsigned long long*)&g_flag[s * 4 + j][0];
                    unsigned long long f0 = __hip_atomic_load(fq,     __ATOMIC_RELAXED, __HIP_MEMORY_SCOPE_AGENT);
                    unsigned long long f1 = __hip_atomic_load(fq + 1, __ATOMIC_RELAXED, __HIP_MEMORY_SCOPE_AGENT);
                    unsigned a = (unsigned)f0, b = (unsigned)(f0 >> 32);
                    unsigned c = (unsigned)f1, d = (unsigned)(f1 >> 32);
                    a = a < b ? a : b; c = c < d ? c : d;
                    a = a < c ? a : c;
                    mn = mn < a ? mn : a;
                }
                if (mn >= i) break;
                __builtin_amdgcn_s_sleep(1);
            }
            __builtin_amdgcn_sched_barrier(0);

            // batched gather: 4 groups x 4 u64 (one pipelined L3 RT)
            unsigned long long gq[4][4];
#pragma unroll
            for (int j = 0; j < 4; j++) {
                const unsigned long long* exq =
                    (const unsigned long long*)&g_ex[i & 1][s * 4 + j][0] + tid * 4;
                gq[j][0] = __hip_atomic_load(exq + 0, __ATOMIC_RELAXED, __HIP_MEMORY_SCOPE_AGENT);
                gq[j][1] = __hip_atomic_load(exq + 1, __ATOMIC_RELAXED, __HIP_MEMORY_SCOPE_AGENT);
                gq[j][2] = __hip_atomic_load(exq + 2, __ATOMIC_RELAXED, __HIP_MEMORY_SCOPE_AGENT);
                gq[j][3] = __hip_atomic_load(exq + 3, __ATOMIC_RELAXED, __HIP_MEMORY_SCOPE_AGENT);
            }
            const int grow = tid >> 5;
            const int gcb = (tid & 31) * 32;
            const int gsw = (grow & 7) << 4;
#pragma unroll
            for (int j = 0; j < 4; j++) {
                union { unsigned long long qq[2]; uint4 v; } c0, c1;
                c0.qq[0] = gq[j][0]; c0.qq[1] = gq[j][1];
                c1.qq[0] = gq[j][2]; c1.qq[1] = gq[j][3];
                char* hw = (char*)lds_h[j] + grow * 1024;
                *(uint4*)(hw + ((gcb)      ^ gsw)) = c0.v;
                *(uint4*)(hw + ((gcb + 16) ^ gsw)) = c1.v;
                if (q == (int)(i & 3)) {   // designated coalesced hs write, slot i-1
                    unsigned short* hr = hs +
                        ((size_t)(s * 64 + j * 16 + grow) * T_ + (i - 1)) * H_ + (tid & 31) * 16;
                    ((uint4*)hr)[0] = c0.v;
                    ((uint4*)hr)[1] = c1.v;
                }
            }
            asm volatile("s_waitcnt lgkmcnt(0)" ::: "memory");
            __builtin_amdgcn_s_barrier();
        }

        // compute 4 groups back-to-back: h^(i+1)_j = tanh(h^i_j Wh^T + P[x_j[:,i]])
#pragma unroll
        for (int j = 0; j < 4; j++) {
            const int xrj = s * 64 + j * 16 + hi * 4;
            const int xv0 = x[(xrj + 0) * T_ + (int)i];
            const int xv1 = x[(xrj + 1) * T_ + (int)i];
            const int xv2 = x[(xrj + 2) * T_ + (int)i];
            const int xv3 = x[(xrj + 3) * T_ + (int)i];
            const unsigned short uu0 = g_P[xv0 * H_ + n];
            const unsigned short uu1 = g_P[xv1 * H_ + n];
            const unsigned short uu2 = g_P[xv2 * H_ + n];
            const unsigned short uu3 = g_P[xv3 * H_ + n];
            f32x4 aca = {0.f, 0.f, 0.f, 0.f}, acb = {0.f, 0.f, 0.f, 0.f};
            const char* hb = (const char*)lds_h[j];
#pragma unroll
            for (int kt = 0; kt < 12; kt += 2) {
                bf16x8 a0 = *(const bf16x8*)(hb + lo * 1024 + ((kt * 64 + hi * 16) ^ sw));
                bf16x8 a1 = *(const bf16x8*)(hb + lo * 1024 + (((kt + 1) * 64 + hi * 16) ^ sw));
                aca = __builtin_amdgcn_mfma_f32_16x16x32_bf16(a0, breg[kt],     aca, 0, 0, 0);
                acb = __builtin_amdgcn_mfma_f32_16x16x32_bf16(a1, breg[kt + 1], acb, 0, 0, 0);
            }
            const char* bbp = (const char*)lds_B + w * 4096 + l * 16;
#pragma unroll
            for (int kk = 0; kk < 4; kk += 2) {
                bf16x8 a0 = *(const bf16x8*)(hb + lo * 1024 + (((12 + kk) * 64 + hi * 16) ^ sw));
                bf16x8 a1 = *(const bf16x8*)(hb + lo * 1024 + (((13 + kk) * 64 + hi * 16) ^ sw));
                bf16x8 b0 = *(const bf16x8*)(bbp + kk * 1024);
                bf16x8 b1 = *(const bf16x8*)(bbp + (kk + 1) * 1024);
                aca = __builtin_amdgcn_mfma_f32_16x16x32_bf16(a0, b0, aca, 0, 0, 0);
                acb = __builtin_amdgcn_mfma_f32_16x16x32_bf16(a1, b1, acb, 0, 0, 0);
            }
            const float t0 = TANH_(aca[0] + acb[0] + bf2f(uu0));
            const float t1 = TANH_(aca[1] + acb[1] + bf2f(uu1));
            const float t2 = TANH_(aca[2] + acb[2] + bf2f(uu2));
            const float t3 = TANH_(aca[3] + acb[3] + bf2f(uu3));
            mp[j][0] = (unsigned)f2bf(t0) | ((unsigned)f2bf(t1) << 16);
            mp[j][1] = (unsigned)f2bf(t2) | ((unsigned)f2bf(t3) << 16);
        }

        if (i < T_ - 1) {
            // ex stores: pack col pairs via 2 shfls/group, 4 store instrs/group
            const int par = (i + 1) & 1;
            __builtin_amdgcn_sched_barrier(0);
#pragma unroll
            for (int j = 0; j < 4; j++) {
                const unsigned nb0 = (unsigned)__shfl_xor((int)mp[j][0], 1);
                const unsigned nb1 = (unsigned)__shfl_xor((int)mp[j][1], 1);
                unsigned* exw = &g_ex[par][s * 4 + j][0] + (n >> 1);
                if (!(lo & 1)) {
                    const unsigned pk0 = (mp[j][0] & 0xffffu) | (nb0 << 16);
                    const unsigned pk1 = (mp[j][0] >> 16) | (nb0 & 0xffff0000u);
                    __hip_atomic_store(exw + (hi * 4 + 0) * 256, pk0, __ATOMIC_RELAXED, __HIP_MEMORY_SCOPE_AGENT);
                    __hip_atomic_store(exw + (hi * 4 + 1) * 256, pk1, __ATOMIC_RELAXED, __HIP_MEMORY_SCOPE_AGENT);
                } else {
                    const unsigned pk2 = (nb1 & 0xffffu) | (mp[j][1] << 16);
                    const unsigned pk3 = (nb1 >> 16) | (mp[j][1] & 0xffff0000u);
                    __hip_atomic_store(exw + (hi * 4 + 2) * 256, pk2, __ATOMIC_RELAXED, __HIP_MEMORY_SCOPE_AGENT);
                    __hip_atomic_store(exw + (hi * 4 + 3) * 256, pk3, __ATOMIC_RELAXED, __HIP_MEMORY_SCOPE_AGENT);
                }
            }
            __builtin_amdgcn_sched_barrier(0);
            asm volatile("s_waitcnt vmcnt(0)" ::: "memory");   // ack all ex (+stale hs)
            __builtin_amdgcn_s_barrier();
            if (tid == 0) {
#pragma unroll
                for (int j = 0; j < 4; j++)
                    __hip_atomic_store(&g_flag[s * 4 + j][q], i + 1,
                                       __ATOMIC_RELAXED, __HIP_MEMORY_SCOPE_AGENT);
            }
        }
    }

    // tail: hs slot T-1 (scattered, own columns) + h_final (fp32) from mp
    float* hfin = out + (size_t)B_ * T_ * O_;
#pragma unroll
    for (int j = 0; j < 4; j++) {
        const int xrj = s * 64 + j * 16 + hi * 4;
        const unsigned short v0 = (unsigned short)(mp[j][0] & 0xffffu);
        const unsigned short v1 = (unsigned short)(mp[j][0] >> 16);
        const unsigned short v2 = (unsigned short)(mp[j][1] & 0xffffu);
        const unsigned short v3 = (unsigned short)(mp[j][1] >> 16);
        hs[((size_t)(xrj + 0) * T_ + T_ - 1) * H_ + n] = v0;
        hs[((size_t)(xrj + 1) * T_ + T_ - 1) * H_ + n] = v1;
        hs[((size_t)(xrj + 2) * T_ + T_ - 1) * H_ + n] = v2;
        hs[((size_t)(xrj + 3) * T_ + T_ - 1) * H_ + n] = v3;
        hfin[(xrj + 0) * H_ + n] = bf2f(v0);
        hfin[(xrj + 1) * H_ + n] = bf2f(v1);
        hfin[(xrj + 2) * H_ + n] = bf2f(v2);
        hfin[(xrj + 3) * H_ + n] = bf2f(v3);
    }
}

// ---------------- K3: outputs = hs @ Wd^T + bd, in-place over hs slots ----------------
__launch_bounds__(512, 2)
__global__ void k_out(const float* __restrict__ bd, float* out) {
    int tid = threadIdx.x;
    int w = tid >> 6, l = tid & 63;
    int hi = l >> 4, lo = l & 15;
    size_t m0 = (size_t)blockIdx.x * 256 + w * 32;
    const unsigned short* hsb = (const unsigned short*)out;
    float bdv[16];
#pragma unroll
    for (int nt = 0; nt < 16; nt++) bdv[nt] = bd[nt * 16 + lo];
    f32x4 acc[2][16];
#pragma unroll
    for (int m = 0; m < 2; m++)
#pragma unroll
        for (int nt = 0; nt < 16; nt++) { acc[m][nt][0] = 0.f; acc[m][nt][1] = 0.f; acc[m][nt][2] = 0.f; acc[m][nt][3] = 0.f; }
#pragma unroll 2
    for (int kt = 0; kt < 16; kt++) {
        bf16x8 a0 = *(const bf16x8*)(hsb + (m0 + lo) * 512 + kt * 32 + hi * 8);
        bf16x8 a1 = *(const bf16x8*)(hsb + (m0 + 16 + lo) * 512 + kt * 32 + hi * 8);
#pragma unroll
        for (int nt = 0; nt < 16; nt++) {
            bf16x8 bf = *(const bf16x8*)(g_Wdf + (size_t)(nt * 16 + kt) * 512 + l * 8);
            acc[0][nt] = __builtin_amdgcn_mfma_f32_16x16x32_bf16(a0, bf, acc[0][nt], 0, 0, 0);
            acc[1][nt] = __builtin_amdgcn_mfma_f32_16x16x32_bf16(a1, bf, acc[1][nt], 0, 0, 0);
        }
    }
#pragma unroll
    for (int m = 0; m < 2; m++)
#pragma unroll
        for (int nt = 0; nt < 16; nt++)
#pragma unroll
            for (int rg = 0; rg < 4; rg++) {
                size_t row = m0 + m * 16 + hi * 4 + rg;
                out[row * O_ + nt * 16 + lo] = acc[m][nt][rg] + bdv[nt];
            }
}

extern "C" void kernel_launch(void* const* d_in, const int* in_sizes, int n_in,
                              void* d_out, int out_size, void* d_ws, size_t ws_size,
                              hipStream_t stream) {
    const int*   x   = (const int*)d_in[0];
    const float* h0  = (const float*)d_in[1];
    const float* emb = (const float*)d_in[2];
    const float* W   = (const float*)d_in[3];
    const float* b   = (const float*)d_in[4];
    const float* Wd  = (const float*)d_in[5];
    const float* bd  = (const float*)d_in[6];
    float* out = (float*)d_out;

    k_embWx<<<dim3(V_), dim3(256), 0, stream>>>(emb, W, b);
    k_fragWh<<<dim3(128), dim3(256), 0, stream>>>(W);
    k_fragWd<<<dim3(64), dim3(256), 0, stream>>>(Wd);
    k_rnn<<<dim3(16), dim3(512), 0, stream>>>(x, h0, out);
    k_out<<<dim3(1024), dim3(512), 0, stream>>>(bd, out);
}

// Round 12
// 4246.368 us; speedup vs baseline: 2.1738x; 2.1738x over previous
//
#include <hip/hip_runtime.h>

typedef short bf16x8 __attribute__((ext_vector_type(8)));
typedef float f32x4 __attribute__((ext_vector_type(4)));

#define B_ 256
#define T_ 1024
#define H_ 512
#define E_ 256
#define O_ 256
#define V_ 256
#define RING 16

// Prepped operands in device globals: graph-safe, rewritten every launch.
__device__ __align__(16) unsigned short g_P[V_ * H_];     // P = emb@Wx^T + b, bf16 (256 KB)
__device__ __align__(16) unsigned short g_Whf[H_ * H_];   // Wh in MFMA B-frag layout (512 KB)
__device__ __align__(16) unsigned short g_Wdf[O_ * H_];   // Wd in MFMA B-frag layout (256 KB)

// Flag-free exchange: 16-deep ring of row-major packed-u32 h images, pre-filled
// with SENTINEL 0xFFFFFFFF (= bf16 NaN pair, never produced by tanh). Consumers
// poll the DATA; no ack, no flag on the critical path. 4 MB, L3-resident.
__device__ __align__(16) unsigned g_exr[RING][16][16 * 256];
__device__ unsigned g_prog[16][64];                       // lazy backpressure, 256B/group

__device__ __forceinline__ unsigned short f2bf(float f) {
    union { float f; unsigned int u; } v; v.f = f;
    unsigned int r = v.u + 0x7fffu + ((v.u >> 16) & 1u);   // RNE
    return (unsigned short)(r >> 16);
}
__device__ __forceinline__ float bf2f(unsigned short s) {
    union { unsigned int u; float f; } v; v.u = ((unsigned int)s) << 16;
    return v.f;
}
__device__ __forceinline__ bool chk64(unsigned long long v) {   // both u32 halves real?
    return ((unsigned)v != 0xFFFFFFFFu) && ((unsigned)(v >> 32) != 0xFFFFFFFFu);
}
#define TANH_(v_) (1.f - __fdividef(2.f, __expf((v_) + (v_)) + 1.f))

// ---------------- K1a: P = b + emb @ Wx^T (bf16); zero prog flags ----------------
__global__ void k_embWx(const float* __restrict__ emb, const float* __restrict__ W,
                        const float* __restrict__ bb) {
    if (blockIdx.x == 0)
        for (int i = threadIdx.x; i < 16 * 64; i += 256) ((unsigned*)g_prog)[i] = 0;
    __shared__ float e[E_];
    int v = blockIdx.x;
    e[threadIdx.x] = emb[(size_t)v * E_ + threadIdx.x];
    __syncthreads();
#pragma unroll
    for (int rep = 0; rep < 2; rep++) {
        int n = threadIdx.x + rep * 256;
        const float4* wr4 = (const float4*)(W + (size_t)n * (E_ + H_));
        float s = bb[n];
        for (int k = 0; k < E_ / 4; k++) {
            float4 wv = wr4[k];
            s += e[4*k] * wv.x + e[4*k+1] * wv.y + e[4*k+2] * wv.z + e[4*k+3] * wv.w;
        }
        g_P[v * H_ + n] = f2bf(s);
    }
}

// ---------------- K1b/K1c: weight -> MFMA B-frag layout; sentinel-fill ring ----------------
__global__ void k_fragWh(const float* __restrict__ W) {
    int gid = blockIdx.x * blockDim.x + threadIdx.x;   // 32768 threads
    {   // sentinel-fill the whole ring every launch (1M u32 / 32 per thread)
        unsigned* e = (unsigned*)g_exr;
#pragma unroll
        for (int k = 0; k < 32; k++) e[(size_t)gid * 32 + k] = 0xFFFFFFFFu;
    }
    int l = gid & 63, tile = gid >> 6;
    int kt = tile & 15, nt = tile >> 4;
    int n = nt * 16 + (l & 15), k0 = kt * 32 + (l >> 4) * 8;
    const float* src = W + (size_t)n * (E_ + H_) + E_ + k0;
#pragma unroll
    for (int j = 0; j < 8; j++) g_Whf[(size_t)gid * 8 + j] = f2bf(src[j]);
}
__global__ void k_fragWd(const float* __restrict__ Wd) {
    int gid = blockIdx.x * blockDim.x + threadIdx.x;
    int l = gid & 63, tile = gid >> 6;
    int kt = tile & 15, nt = tile >> 4;
    int n = nt * 16 + (l & 15), k0 = kt * 32 + (l >> 4) * 8;
    const float* src = Wd + (size_t)n * H_ + k0;
#pragma unroll
    for (int j = 0; j < 8; j++) g_Wdf[(size_t)gid * 8 + j] = f2bf(src[j]);
}

// ---------------- K2: recurrence — sentinel-polled exchange (no ack, no flag) ----------------
// 64 blocks = 16 groups g x 4 quarters q; 512 thr = 8 waves; wave owns ntile q*8+w
// (breg 64 VGPRs, R9 core). Per step: poll OWN 32-B ring slice until all u32 !=
// SENTINEL (detect = data flight + ~1 reload; replaces R9's ack+flag+poll chain,
// which R7=R9=3.4ms showed costs ~2 L3 RTs) -> ds_write image (dbuf, 1 barrier) ->
// MFMA+tanh -> plain atomic ex stores of h_{t+1}, NO wait -> next poll.
// Hygiene: slot(t-2) sentinel-refilled at iter t (all readers provably done: we
// observed h_t => every peer finished iter t-1 => finished reading h_{t-2});
// slot reuse (depth 16) guarded by lazy prog flags: posted every 2 steps after a
// vmcnt(0) drains fills; producer checks cached min >= t-13 (lockstep: never
// spins, repolls ~1/11 steps). Deadlock-free: peers advance on already-published
// data only. hs written coalesced by designated quarter from gather regs.
__global__ void __launch_bounds__(512) k_rnn(const int* __restrict__ x,
                                             const float* __restrict__ h0,
                                             float* __restrict__ out) {
    __shared__ __align__(16) unsigned short lds_h[2][16 * 512];   // dbuf images
    const int tid = threadIdx.x;
    const int w = tid >> 6, l = tid & 63;
    const int hi = l >> 4, lo = l & 15;
    const int g = blockIdx.x >> 2, q = blockIdx.x & 3;
    const int nt = q * 8 + w;
    const int n = nt * 16 + lo;
    const int sw = (lo & 7) << 4;               // A-read swizzle

    // pinned Wh B-frags: 16 x 4 = 64 VGPRs
    bf16x8 breg[16];
#pragma unroll
    for (int kt = 0; kt < 16; kt++)
        breg[kt] = *(const bf16x8*)(g_Whf + (nt * 16 + kt) * 512 + l * 8);

    // stage h0 -> lds_h[0] (fp32 -> packed bf16, swizzled)
    {
        const int row = tid >> 5;
        const int cb = (tid & 31) * 32;
        const int gsw = (row & 7) << 4;
        const float* hp = h0 + (size_t)(g * 16 + row) * H_ + (tid & 31) * 16;
        unsigned pk[8];
#pragma unroll
        for (int i = 0; i < 8; i++)
            pk[i] = (unsigned)f2bf(hp[2 * i]) | ((unsigned)f2bf(hp[2 * i + 1]) << 16);
        char* hw = (char*)lds_h[0] + row * 1024;
        *(uint4*)(hw + ((cb)      ^ gsw)) = make_uint4(pk[0], pk[1], pk[2], pk[3]);
        *(uint4*)(hw + ((cb + 16) ^ gsw)) = make_uint4(pk[4], pk[5], pk[6], pk[7]);
    }
    __syncthreads();

    const int xr = g * 16 + hi * 4;             // thread's 4 batch rows
    unsigned short* hs = (unsigned short*)out;  // hs bf16 in-place in d_out
    unsigned mp0 = 0, mp1 = 0;                  // packed h rows (0,1),(2,3)
    unsigned progseen = 0;

#pragma unroll 1
    for (unsigned t = 0; t < T_; t++) {
        if (t) {
            // poll-gather own 32-B slice of slot t%16 until fully non-sentinel
            const unsigned long long* exq =
                (const unsigned long long*)&g_exr[t & (RING - 1)][g][0] + tid * 4;
            unsigned long long q0, q1, q2, q3;
            for (;;) {
                q0 = __hip_atomic_load(exq + 0, __ATOMIC_RELAXED, __HIP_MEMORY_SCOPE_AGENT);
                q1 = __hip_atomic_load(exq + 1, __ATOMIC_RELAXED, __HIP_MEMORY_SCOPE_AGENT);
                q2 = __hip_atomic_load(exq + 2, __ATOMIC_RELAXED, __HIP_MEMORY_SCOPE_AGENT);
                q3 = __hip_atomic_load(exq + 3, __ATOMIC_RELAXED, __HIP_MEMORY_SCOPE_AGENT);
                const bool ok = chk64(q0) && chk64(q1) && chk64(q2) && chk64(q3);
                if (__all(ok)) break;
            }
            // image write (swizzled) into the t&1 buffer
            const int grow = tid >> 5;
            const int gcb = (tid & 31) * 32;
            const int gsw = (grow & 7) << 4;
            union { unsigned long long qq[2]; uint4 v; } c0, c1;
            c0.qq[0] = q0; c0.qq[1] = q1;
            c1.qq[0] = q2; c1.qq[1] = q3;
            char* hw = (char*)lds_h[t & 1] + grow * 1024;
            *(uint4*)(hw + ((gcb)      ^ gsw)) = c0.v;
            *(uint4*)(hw + ((gcb + 16) ^ gsw)) = c1.v;
            // sentinel-refill slot (t-2): designated rows q*4..q*4+4 (readers done)
            if (t >= 2) {
                unsigned long long* fw =
                    (unsigned long long*)&g_exr[(t - 2) & (RING - 1)][g][0] +
                    (q * 4 + (tid >> 7)) * 128 + (tid & 127);
                __hip_atomic_store(fw, 0xFFFFFFFFFFFFFFFFULL,
                                   __ATOMIC_RELAXED, __HIP_MEMORY_SCOPE_AGENT);
            }
            if (!(t & 1)) asm volatile("s_waitcnt vmcnt(0)" ::: "memory");  // drain fills
            asm volatile("s_waitcnt lgkmcnt(0)" ::: "memory");
            __builtin_amdgcn_s_barrier();
            if (!(t & 1) && t >= 2 && tid == 0)
                __hip_atomic_store(&g_prog[g][q], t, __ATOMIC_RELAXED, __HIP_MEMORY_SCOPE_AGENT);
            // designated coalesced hs write, slot t-1 (post-barrier: never waited on)
            if (q == (int)((t - 1) & 3)) {
                unsigned short* hr = hs + ((size_t)(g * 16 + grow) * T_ + (t - 1)) * H_ +
                                     (tid & 31) * 16;
                ((uint4*)hr)[0] = c0.v;
                ((uint4*)hr)[1] = c1.v;
            }
        }

        // compute: h_{t+1} = tanh(h_t Wh^T + P[x[:,t]])
        const int xv0 = x[(xr + 0) * T_ + (int)t];
        const int xv1 = x[(xr + 1) * T_ + (int)t];
        const int xv2 = x[(xr + 2) * T_ + (int)t];
        const int xv3 = x[(xr + 3) * T_ + (int)t];
        const unsigned short uu0 = g_P[xv0 * H_ + n];
        const unsigned short uu1 = g_P[xv1 * H_ + n];
        const unsigned short uu2 = g_P[xv2 * H_ + n];
        const unsigned short uu3 = g_P[xv3 * H_ + n];
        f32x4 aca = {0.f, 0.f, 0.f, 0.f}, acb = {0.f, 0.f, 0.f, 0.f};
        const char* hb = (const char*)lds_h[t & 1];
#pragma unroll
        for (int kt = 0; kt < 16; kt += 2) {
            bf16x8 a0 = *(const bf16x8*)(hb + lo * 1024 + ((kt * 64 + hi * 16) ^ sw));
            bf16x8 a1 = *(const bf16x8*)(hb + lo * 1024 + (((kt + 1) * 64 + hi * 16) ^ sw));
            aca = __builtin_amdgcn_mfma_f32_16x16x32_bf16(a0, breg[kt],     aca, 0, 0, 0);
            acb = __builtin_amdgcn_mfma_f32_16x16x32_bf16(a1, breg[kt + 1], acb, 0, 0, 0);
        }
        const float t0 = TANH_(aca[0] + acb[0] + bf2f(uu0));
        const float t1 = TANH_(aca[1] + acb[1] + bf2f(uu1));
        const float t2 = TANH_(aca[2] + acb[2] + bf2f(uu2));
        const float t3 = TANH_(aca[3] + acb[3] + bf2f(uu3));
        mp0 = (unsigned)f2bf(t0) | ((unsigned)f2bf(t1) << 16);
        mp1 = (unsigned)f2bf(t2) | ((unsigned)f2bf(t3) << 16);

        if (t < T_ - 1) {
            // lazy backpressure: slot (t+1) reused from h_{t-15}, refilled at iter
            // t-13; need all peers' prog >= t-13 (cached; lockstep => pre-satisfied)
            if (t >= RING && progseen + 13 < t) {
                const unsigned long long* fq = (const unsigned long long*)&g_prog[g][0];
                for (;;) {
                    unsigned long long f0 = __hip_atomic_load(fq,     __ATOMIC_RELAXED, __HIP_MEMORY_SCOPE_AGENT);
                    unsigned long long f1 = __hip_atomic_load(fq + 1, __ATOMIC_RELAXED, __HIP_MEMORY_SCOPE_AGENT);
                    unsigned a = (unsigned)f0, b = (unsigned)(f0 >> 32);
                    unsigned c = (unsigned)f1, d = (unsigned)(f1 >> 32);
                    a = a < b ? a : b; c = c < d ? c : d;
                    const unsigned mn = a < c ? a : c;
                    if (mn + 13 >= t) { progseen = mn; break; }
                    __builtin_amdgcn_s_sleep(1);
                }
            }
            // publish h_{t+1} into slot (t+1)%16: plain atomic stores, NO wait
            const unsigned nb0 = (unsigned)__shfl_xor((int)mp0, 1);
            const unsigned nb1 = (unsigned)__shfl_xor((int)mp1, 1);
            unsigned* exw = &g_exr[(t + 1) & (RING - 1)][g][0] + (n >> 1);
            if (!(lo & 1)) {
                const unsigned pk0 = (mp0 & 0xffffu) | (nb0 << 16);
                const unsigned pk1 = (mp0 >> 16) | (nb0 & 0xffff0000u);
                __hip_atomic_store(exw + (hi * 4 + 0) * 256, pk0, __ATOMIC_RELAXED, __HIP_MEMORY_SCOPE_AGENT);
                __hip_atomic_store(exw + (hi * 4 + 1) * 256, pk1, __ATOMIC_RELAXED, __HIP_MEMORY_SCOPE_AGENT);
            } else {
                const unsigned pk2 = (nb1 & 0xffffu) | (mp1 << 16);
                const unsigned pk3 = (nb1 >> 16) | (mp1 & 0xffff0000u);
                __hip_atomic_store(exw + (hi * 4 + 2) * 256, pk2, __ATOMIC_RELAXED, __HIP_MEMORY_SCOPE_AGENT);
                __hip_atomic_store(exw + (hi * 4 + 3) * 256, pk3, __ATOMIC_RELAXED, __HIP_MEMORY_SCOPE_AGENT);
            }
        }
    }

    // tail: hs slot T-1 (scattered, own columns) + h_final (fp32)
    {
        const unsigned short v0 = (unsigned short)(mp0 & 0xffffu);
        const unsigned short v1 = (unsigned short)(mp0 >> 16);
        const unsigned short v2 = (unsigned short)(mp1 & 0xffffu);
        const unsigned short v3 = (unsigned short)(mp1 >> 16);
        hs[((size_t)(xr + 0) * T_ + T_ - 1) * H_ + n] = v0;
        hs[((size_t)(xr + 1) * T_ + T_ - 1) * H_ + n] = v1;
        hs[((size_t)(xr + 2) * T_ + T_ - 1) * H_ + n] = v2;
        hs[((size_t)(xr + 3) * T_ + T_ - 1) * H_ + n] = v3;
        float* hfin = out + (size_t)B_ * T_ * O_;
        hfin[(xr + 0) * H_ + n] = bf2f(v0);
        hfin[(xr + 1) * H_ + n] = bf2f(v1);
        hfin[(xr + 2) * H_ + n] = bf2f(v2);
        hfin[(xr + 3) * H_ + n] = bf2f(v3);
    }
}

// ---------------- K3: outputs = hs @ Wd^T + bd, in-place over hs slots ----------------
__launch_bounds__(512, 2)
__global__ void k_out(const float* __restrict__ bd, float* out) {
    int tid = threadIdx.x;
    int w = tid >> 6, l = tid & 63;
    int hi = l >> 4, lo = l & 15;
    size_t m0 = (size_t)blockIdx.x * 256 + w * 32;
    const unsigned short* hsb = (const unsigned short*)out;
    float bdv[16];
#pragma unroll
    for (int nt = 0; nt < 16; nt++) bdv[nt] = bd[nt * 16 + lo];
    f32x4 acc[2][16];
#pragma unroll
    for (int m = 0; m < 2; m++)
#pragma unroll
        for (int nt = 0; nt < 16; nt++) { acc[m][nt][0] = 0.f; acc[m][nt][1] = 0.f; acc[m][nt][2] = 0.f; acc[m][nt][3] = 0.f; }
#pragma unroll 2
    for (int kt = 0; kt < 16; kt++) {
        bf16x8 a0 = *(const bf16x8*)(hsb + (m0 + lo) * 512 + kt * 32 + hi * 8);
        bf16x8 a1 = *(const bf16x8*)(hsb + (m0 + 16 + lo) * 512 + kt * 32 + hi * 8);
#pragma unroll
        for (int nt = 0; nt < 16; nt++) {
            bf16x8 bf = *(const bf16x8*)(g_Wdf + (size_t)(nt * 16 + kt) * 512 + l * 8);
            acc[0][nt] = __builtin_amdgcn_mfma_f32_16x16x32_bf16(a0, bf, acc[0][nt], 0, 0, 0);
            acc[1][nt] = __builtin_amdgcn_mfma_f32_16x16x32_bf16(a1, bf, acc[1][nt], 0, 0, 0);
        }
    }
#pragma unroll
    for (int m = 0; m < 2; m++)
#pragma unroll
        for (int nt = 0; nt < 16; nt++)
#pragma unroll
            for (int rg = 0; rg < 4; rg++) {
                size_t row = m0 + m * 16 + hi * 4 + rg;
                out[row * O_ + nt * 16 + lo] = acc[m][nt][rg] + bdv[nt];
            }
}

extern "C" void kernel_launch(void* const* d_in, const int* in_sizes, int n_in,
                              void* d_out, int out_size, void* d_ws, size_t ws_size,
                              hipStream_t stream) {
    const int*   x   = (const int*)d_in[0];
    const float* h0  = (const float*)d_in[1];
    const float* emb = (const float*)d_in[2];
    const float* W   = (const float*)d_in[3];
    const float* b   = (const float*)d_in[4];
    const float* Wd  = (const float*)d_in[5];
    const float* bd  = (const float*)d_in[6];
    float* out = (float*)d_out;

    k_embWx<<<dim3(V_), dim3(256), 0, stream>>>(emb, W, b);
    k_fragWh<<<dim3(128), dim3(256), 0, stream>>>(W);
    k_fragWd<<<dim3(64), dim3(256), 0, stream>>>(Wd);
    k_rnn<<<dim3(64), dim3(512), 0, stream>>>(x, h0, out);
    k_out<<<dim3(1024), dim3(512), 0, stream>>>(bd, out);
}

// Round 13
// 3236.265 us; speedup vs baseline: 2.8523x; 1.3121x over previous
//
#include <hip/hip_runtime.h>

typedef short bf16x8 __attribute__((ext_vector_type(8)));
typedef float f32x4 __attribute__((ext_vector_type(4)));
typedef int i32x4 __attribute__((ext_vector_type(4)));

#define B_ 256
#define T_ 1024
#define H_ 512
#define E_ 256
#define O_ 256
#define V_ 256

// Prepped operands in device globals: graph-safe, rewritten every launch.
__device__ __align__(16) unsigned short g_P[V_ * H_];     // P = emb@Wx^T + b, bf16 (256 KB)
__device__ __align__(16) signed char    g_Whq[H_ * H_];   // Wh int8, MFMA B-frag layout (256 KB)
__device__ float                        g_scale[H_];      // per-row quant scale s_n (W ~ q*s_n)
__device__ __align__(16) unsigned short g_Wdf[O_ * H_];   // Wd bf16, MFMA B-frag layout (256 KB)

__device__ __forceinline__ unsigned short f2bf(float f) {
    union { float f; unsigned int u; } v; v.f = f;
    unsigned int r = v.u + 0x7fffu + ((v.u >> 16) & 1u);   // RNE
    return (unsigned short)(r >> 16);
}
__device__ __forceinline__ float bf2f(unsigned short s) {
    union { unsigned int u; float f; } v; v.u = ((unsigned int)s) << 16;
    return v.f;
}
#define TANH_(v_) (1.f - __fdividef(2.f, __expf((v_) + (v_)) + 1.f))

// ---------------- K1a: P = b + emb @ Wx^T (bf16) ----------------
__global__ void k_embWx(const float* __restrict__ emb, const float* __restrict__ W,
                        const float* __restrict__ bb) {
    __shared__ float e[E_];
    int v = blockIdx.x;
    e[threadIdx.x] = emb[(size_t)v * E_ + threadIdx.x];
    __syncthreads();
#pragma unroll
    for (int rep = 0; rep < 2; rep++) {
        int n = threadIdx.x + rep * 256;
        const float4* wr4 = (const float4*)(W + (size_t)n * (E_ + H_));
        float s = bb[n];
        for (int k = 0; k < E_ / 4; k++) {
            float4 wv = wr4[k];
            s += e[4*k] * wv.x + e[4*k+1] * wv.y + e[4*k+2] * wv.z + e[4*k+3] * wv.w;
        }
        g_P[v * H_ + n] = f2bf(s);
    }
}

// ---------------- K1b: Wh -> int8 + per-row scale, MFMA i8 B-frag layout ----------------
// 512 blocks (one per output row n) x 64 lanes. Frag mapping mirrors the verified
// bf16 16x16x32 one (elem j of lane l = W[n=l&15][k=(l>>4)*8+j]), 1 B elems.
__global__ void k_prep8(const float* __restrict__ W) {
    const int n = blockIdx.x;
    const int li = threadIdx.x;
    const float* src = W + (size_t)n * (E_ + H_) + E_;   // Wh row n = W[n][256:768]
    float v[8];
    float mx = 0.f;
#pragma unroll
    for (int m = 0; m < 8; m++) { v[m] = src[li * 8 + m]; mx = fmaxf(mx, fabsf(v[m])); }
#pragma unroll
    for (int off = 1; off < 64; off <<= 1)
        mx = fmaxf(mx, __shfl_xor(mx, off));
    const float s = fmaxf(mx, 1e-20f) / 127.f;
    if (li == 0) g_scale[n] = s;
    const float inv = 1.f / s;
    unsigned long long pk = 0;
#pragma unroll
    for (int m = 0; m < 8; m++) {
        int q = __float2int_rn(v[m] * inv);
        q = q > 127 ? 127 : (q < -127 ? -127 : q);
        pk |= ((unsigned long long)(unsigned char)(signed char)q) << (8 * m);
    }
    // lane li covers k = li*8..li*8+7: kt = li>>2, hi-group = li&3
    *(unsigned long long*)(g_Whq + (((size_t)(n >> 4) * 16 + (li >> 2)) * 512)
                           + (((n & 15) + ((li & 3) << 4)) * 8)) = pk;
}

// ---------------- K1c: Wd -> MFMA bf16 B-frag layout ----------------
__global__ void k_fragWd(const float* __restrict__ Wd) {
    int gid = blockIdx.x * blockDim.x + threadIdx.x;
    int l = gid & 63, tile = gid >> 6;
    int kt = tile & 15, nt = tile >> 4;
    int n = nt * 16 + (l & 15), k0 = kt * 32 + (l >> 4) * 8;
    const float* src = Wd + (size_t)n * H_ + k0;
#pragma unroll
    for (int j = 0; j < 8; j++) g_Wdf[(size_t)gid * 8 + j] = f2bf(src[j]);
}

// ---------------- K2: recurrence — int8 Wh FULLY on-CU; no exchange, no stream ----------------
// 16 blocks x 16 batch rows; 512 thr = 8 waves; wave owns ntiles 4w..4w+3 (64 n).
// R7-R12 model: cross-CU exchange plateaus at ~3.3ms (per-CU fabric rate limit);
// R1-R6: bf16 Wh (512 KB) can't fit on-CU. int8 Wh = 256 KB FITS: kt 0..6 pinned
// in 56 VGPRs (total demand ~115 < the immovable 128 grant), kt 7..15 in 144 KB
// LDS, h images (i8, quantized tanh*127) double-buffered 2x8 KB -> LDS = 160 KB
// exact. Per step: 16x ds_read_b64 A-frags (XOR-swizzled rows), 64 MFMA
// i32_16x16x32_i8 per wave, epilogue f32 = acc*s_n/127 + P[x], tanh, bf16 hs
// store (never drained) + i8 image byte-write, ONE lgkm-only barrier.
__global__ void __launch_bounds__(512) k_rnn(const int* __restrict__ x,
                                             const float* __restrict__ h0,
                                             float* __restrict__ out) {
    __shared__ __align__(16) signed char lds_img[2][16 * 512];        // 16 KB dbuf
    __shared__ __align__(16) signed char lds_W[8 * 4 * 9 * 512];      // 144 KB kt 7..15
    const int tid = threadIdx.x;
    const int w = tid >> 6, l = tid & 63;
    const int hi = l >> 4, lo = l & 15;
    const int r0 = blockIdx.x * 16;
    const int w4 = w * 4;
    const int nb = w * 64 + lo;                 // n = nb + nt*16
    const int sw = (lo & 7) << 4;               // A-read swizzle

    // pinned B-frags kt 0..6 (4 nt x 7 kt x 8 B = 56 VGPRs)
    long breg[4][7];
#pragma unroll
    for (int nt = 0; nt < 4; nt++)
#pragma unroll
        for (int kt = 0; kt < 7; kt++)
            breg[nt][kt] = *(const long*)(g_Whq + ((w4 + nt) * 16 + kt) * 512 + l * 8);

    // LDS-resident B-frags kt 7..15 (8 waves x 4 nt x 9 kt x 512 B = 144 KB)
#pragma unroll
    for (int nt = 0; nt < 4; nt++)
#pragma unroll
        for (int ktl = 0; ktl < 9; ktl++) {
            long v = *(const long*)(g_Whq + ((w4 + nt) * 16 + 7 + ktl) * 512 + l * 8);
            *(long*)(lds_W + (((w4 + nt) * 9 + ktl) * 512) + l * 8) = v;
        }

    // per-output scales: gs[nt] = s_n / 127  (dequant of both W and h)
    float gs[4];
#pragma unroll
    for (int nt = 0; nt < 4; nt++) gs[nt] = g_scale[nb + nt * 16] * (1.f / 127.f);

    // stage h0 -> image 0 (f32 -> i8, swizzled): thread = (row, 16-byte chunk)
    {
        const int row = tid >> 5;
        const int c0 = (tid & 31) * 16;
        const float* hp = h0 + (size_t)(r0 + row) * H_ + c0;
        union { unsigned char b[16]; uint4 v; } pk;
#pragma unroll
        for (int i = 0; i < 16; i++) {
            int q = __float2int_rn(fminf(fmaxf(hp[i], -1.f), 1.f) * 127.f);
            pk.b[i] = (unsigned char)(signed char)q;
        }
        *(uint4*)(lds_img[0] + row * 512 + (c0 ^ ((row & 7) << 4))) = pk.v;
    }

    // x for t=0 (thread's 4 batch rows r = hi*4+rg)
    const int xr = r0 + hi * 4;
    int xs0 = x[(xr + 0) * T_], xs1 = x[(xr + 1) * T_],
        xs2 = x[(xr + 2) * T_], xs3 = x[(xr + 3) * T_];

    const int eo0 = (xr + 0) * (T_ * H_) + nb;
    const int eo1 = (xr + 1) * (T_ * H_) + nb;
    const int eo2 = (xr + 2) * (T_ * H_) + nb;
    const int eo3 = (xr + 3) * (T_ * H_) + nb;

    unsigned short* hs = (unsigned short*)out;   // hs bf16 in-place in d_out
    float* hfin = out + (size_t)B_ * T_ * O_;
    __syncthreads();

#pragma unroll 1
    for (int t = 0; t < T_; t++) {
        // u = P[x[r,t]][n]: 16 bf16 loads, consumed in epilogue (latency hidden)
        unsigned short u[4][4];
        {
            const int xb0 = xs0 << 9, xb1 = xs1 << 9, xb2 = xs2 << 9, xb3 = xs3 << 9;
#pragma unroll
            for (int nt = 0; nt < 4; nt++) {
                const int nn = nb + nt * 16;
                u[nt][0] = g_P[xb0 + nn];
                u[nt][1] = g_P[xb1 + nn];
                u[nt][2] = g_P[xb2 + nn];
                u[nt][3] = g_P[xb3 + nn];
            }
        }
        // x prefetch t+1
        {
            const int tn = (t < T_ - 1) ? t + 1 : t;
            xs0 = x[(xr + 0) * T_ + tn]; xs1 = x[(xr + 1) * T_ + tn];
            xs2 = x[(xr + 2) * T_ + tn]; xs3 = x[(xr + 3) * T_ + tn];
        }

        // MFMA: acc_nt(i32) = sum_k qh * qw
        i32x4 acc[4];
#pragma unroll
        for (int nt = 0; nt < 4; nt++) { acc[nt][0] = 0; acc[nt][1] = 0; acc[nt][2] = 0; acc[nt][3] = 0; }
        const signed char* img = lds_img[t & 1];
#pragma unroll
        for (int kt = 0; kt < 7; kt++) {
            long a = *(const long*)(img + lo * 512 + ((kt * 32 + hi * 8) ^ sw));
            acc[0] = __builtin_amdgcn_mfma_i32_16x16x32_i8(a, breg[0][kt], acc[0], 0, 0, 0);
            acc[1] = __builtin_amdgcn_mfma_i32_16x16x32_i8(a, breg[1][kt], acc[1], 0, 0, 0);
            acc[2] = __builtin_amdgcn_mfma_i32_16x16x32_i8(a, breg[2][kt], acc[2], 0, 0, 0);
            acc[3] = __builtin_amdgcn_mfma_i32_16x16x32_i8(a, breg[3][kt], acc[3], 0, 0, 0);
        }
#pragma unroll
        for (int ktl = 0; ktl < 9; ktl++) {
            const int kt = 7 + ktl;
            long a = *(const long*)(img + lo * 512 + ((kt * 32 + hi * 8) ^ sw));
            long b0 = *(const long*)(lds_W + (((w4 + 0) * 9 + ktl) * 512) + l * 8);
            long b1 = *(const long*)(lds_W + (((w4 + 1) * 9 + ktl) * 512) + l * 8);
            long b2 = *(const long*)(lds_W + (((w4 + 2) * 9 + ktl) * 512) + l * 8);
            long b3 = *(const long*)(lds_W + (((w4 + 3) * 9 + ktl) * 512) + l * 8);
            acc[0] = __builtin_amdgcn_mfma_i32_16x16x32_i8(a, b0, acc[0], 0, 0, 0);
            acc[1] = __builtin_amdgcn_mfma_i32_16x16x32_i8(a, b1, acc[1], 0, 0, 0);
            acc[2] = __builtin_amdgcn_mfma_i32_16x16x32_i8(a, b2, acc[2], 0, 0, 0);
            acc[3] = __builtin_amdgcn_mfma_i32_16x16x32_i8(a, b3, acc[3], 0, 0, 0);
        }

        // epilogue: f = acc*s/127 + u; h = tanh(f); hs bf16 (never drained);
        // image[c^1] gets round(h*127) as i8
        signed char* imw = lds_img[(t & 1) ^ 1];
        const int tb = t << 9;
#pragma unroll
        for (int nt = 0; nt < 4; nt++) {
            const int nn = nb + nt * 16;
#pragma unroll
            for (int rg = 0; rg < 4; rg++) {
                const int r = hi * 4 + rg;          // C/D row = (lane>>4)*4 + reg [m89]
                float f = (float)acc[nt][rg] * gs[nt] + bf2f(u[nt][rg]);
                float th = TANH_(f);
                const int eo = (rg == 0) ? eo0 : (rg == 1) ? eo1 : (rg == 2) ? eo2 : eo3;
                hs[eo + tb + nt * 16] = f2bf(th);
                int q = __float2int_rn(th * 127.f);
                imw[r * 512 + (nn ^ ((r & 7) << 4))] = (signed char)q;
                if (t == T_ - 1) hfin[(r0 + r) * H_ + nn] = th;
            }
        }

        // single barrier: LDS visibility only (hs stores fly freely)
        __builtin_amdgcn_sched_barrier(0);
        asm volatile("s_waitcnt lgkmcnt(0)" ::: "memory");
        __builtin_amdgcn_s_barrier();
        __builtin_amdgcn_sched_barrier(0);
    }
}

// ---------------- K3: outputs = hs @ Wd^T + bd, in-place over hs slots ----------------
__launch_bounds__(512, 2)
__global__ void k_out(const float* __restrict__ bd, float* out) {
    int tid = threadIdx.x;
    int w = tid >> 6, l = tid & 63;
    int hi = l >> 4, lo = l & 15;
    size_t m0 = (size_t)blockIdx.x * 256 + w * 32;
    const unsigned short* hsb = (const unsigned short*)out;
    float bdv[16];
#pragma unroll
    for (int nt = 0; nt < 16; nt++) bdv[nt] = bd[nt * 16 + lo];
    f32x4 acc[2][16];
#pragma unroll
    for (int m = 0; m < 2; m++)
#pragma unroll
        for (int nt = 0; nt < 16; nt++) { acc[m][nt][0] = 0.f; acc[m][nt][1] = 0.f; acc[m][nt][2] = 0.f; acc[m][nt][3] = 0.f; }
#pragma unroll 2
    for (int kt = 0; kt < 16; kt++) {
        bf16x8 a0 = *(const bf16x8*)(hsb + (m0 + lo) * 512 + kt * 32 + hi * 8);
        bf16x8 a1 = *(const bf16x8*)(hsb + (m0 + 16 + lo) * 512 + kt * 32 + hi * 8);
#pragma unroll
        for (int nt = 0; nt < 16; nt++) {
            bf16x8 bf = *(const bf16x8*)(g_Wdf + (size_t)(nt * 16 + kt) * 512 + l * 8);
            acc[0][nt] = __builtin_amdgcn_mfma_f32_16x16x32_bf16(a0, bf, acc[0][nt], 0, 0, 0);
            acc[1][nt] = __builtin_amdgcn_mfma_f32_16x16x32_bf16(a1, bf, acc[1][nt], 0, 0, 0);
        }
    }
#pragma unroll
    for (int m = 0; m < 2; m++)
#pragma unroll
        for (int nt = 0; nt < 16; nt++)
#pragma unroll
            for (int rg = 0; rg < 4; rg++) {
                size_t row = m0 + m * 16 + hi * 4 + rg;
                out[row * O_ + nt * 16 + lo] = acc[m][nt][rg] + bdv[nt];
            }
}

extern "C" void kernel_launch(void* const* d_in, const int* in_sizes, int n_in,
                              void* d_out, int out_size, void* d_ws, size_t ws_size,
                              hipStream_t stream) {
    const int*   x   = (const int*)d_in[0];
    const float* h0  = (const float*)d_in[1];
    const float* emb = (const float*)d_in[2];
    const float* W   = (const float*)d_in[3];
    const float* b   = (const float*)d_in[4];
    const float* Wd  = (const float*)d_in[5];
    const float* bd  = (const float*)d_in[6];
    float* out = (float*)d_out;

    k_embWx<<<dim3(V_), dim3(256), 0, stream>>>(emb, W, b);
    k_prep8<<<dim3(H_), dim3(64), 0, stream>>>(W);
    k_fragWd<<<dim3(64), dim3(256), 0, stream>>>(Wd);
    k_rnn<<<dim3(16), dim3(512), 0, stream>>>(x, h0, out);
    k_out<<<dim3(1024), dim3(512), 0, stream>>>(bd, out);
}

// Round 14
// 2697.064 us; speedup vs baseline: 3.4226x; 1.1999x over previous
//
#include <hip/hip_runtime.h>

typedef short bf16x8 __attribute__((ext_vector_type(8)));
typedef float f32x4 __attribute__((ext_vector_type(4)));
typedef int i32x4 __attribute__((ext_vector_type(4)));

#define B_ 256
#define T_ 1024
#define H_ 512
#define E_ 256
#define O_ 256
#define V_ 256

// Prepped operands in device globals: graph-safe, rewritten every launch.
__device__ __align__(16) unsigned g_P2[V_ * 256];         // P packed u32 pairs (R5-verified layout)
__device__ __align__(16) signed char    g_Whq[H_ * H_];   // Wh int8, MFMA B-frag layout (256 KB)
__device__ float                        g_scale[H_];      // per-row quant scale s_n
__device__ __align__(16) unsigned short g_Wdf[O_ * H_];   // Wd bf16, MFMA B-frag layout (256 KB)

__device__ __forceinline__ unsigned short f2bf(float f) {
    union { float f; unsigned int u; } v; v.f = f;
    unsigned int r = v.u + 0x7fffu + ((v.u >> 16) & 1u);   // RNE
    return (unsigned short)(r >> 16);
}
__device__ __forceinline__ float bf2f(unsigned short s) {
    union { unsigned int u; float f; } v; v.u = ((unsigned int)s) << 16;
    return v.f;
}
// tanh(f) = 1 - 2/(exp2(f*2log2e)+1): raw v_exp/v_rcp (no libm fixup chains)
__device__ __forceinline__ float tanh_fast(float f) {
    float kf = f * 2.885390081777927f;
    float E; asm("v_exp_f32 %0, %1" : "=v"(E) : "v"(kf));
    float d = E + 1.f;
    float r; asm("v_rcp_f32 %0, %1" : "=v"(r) : "v"(d));
    return __builtin_fmaf(-2.f, r, 1.f);
}
// row-swizzle: ((r&7)<<4)^(r&8) — bit3 term makes rows {x,4+x,8+x,12+x} (the 4 rows
// of one epilogue write instr) land in distinct bank regions (R13: 2 distinct -> 8-way)
#define SW(r_) ((((r_) & 7) << 4) ^ ((r_) & 8))

// ---------------- K1a: P2 = packed(b + emb @ Wx^T) (R5-verified packing) ----------------
__global__ void k_embWx(const float* __restrict__ emb, const float* __restrict__ W,
                        const float* __restrict__ bb) {
    __shared__ float e[E_];
    int v = blockIdx.x;
    e[threadIdx.x] = emb[(size_t)v * E_ + threadIdx.x];
    __syncthreads();
#pragma unroll
    for (int rep = 0; rep < 2; rep++) {
        int n = threadIdx.x + rep * 256;
        const float4* wr4 = (const float4*)(W + (size_t)n * (E_ + H_));
        float s = bb[n];
        for (int k = 0; k < E_ / 4; k++) {
            float4 wv = wr4[k];
            s += e[4*k] * wv.x + e[4*k+1] * wv.y + e[4*k+2] * wv.z + e[4*k+3] * wv.w;
        }
        int w = n >> 6, r6 = n & 63;
        int lo = r6 & 15, nt = r6 >> 4;
        int p = nt >> 1, half = nt & 1;
        ((unsigned short*)g_P2)[(v * 256 + w * 32 + lo * 2 + p) * 2 + half] = f2bf(s);
    }
}

// ---------------- K1b: Wh -> int8 + per-row scale, MFMA i8 B-frag layout ----------------
__global__ void k_prep8(const float* __restrict__ W) {
    const int n = blockIdx.x;
    const int li = threadIdx.x;
    const float* src = W + (size_t)n * (E_ + H_) + E_;   // Wh row n = W[n][256:768]
    float v[8];
    float mx = 0.f;
#pragma unroll
    for (int m = 0; m < 8; m++) { v[m] = src[li * 8 + m]; mx = fmaxf(mx, fabsf(v[m])); }
#pragma unroll
    for (int off = 1; off < 64; off <<= 1)
        mx = fmaxf(mx, __shfl_xor(mx, off));
    const float s = fmaxf(mx, 1e-20f) / 127.f;
    if (li == 0) g_scale[n] = s;
    const float inv = 1.f / s;
    unsigned long long pk = 0;
#pragma unroll
    for (int m = 0; m < 8; m++) {
        int q = __float2int_rn(v[m] * inv);
        q = q > 127 ? 127 : (q < -127 ? -127 : q);
        pk |= ((unsigned long long)(unsigned char)(signed char)q) << (8 * m);
    }
    *(unsigned long long*)(g_Whq + (((size_t)(n >> 4) * 16 + (li >> 2)) * 512)
                           + (((n & 15) + ((li & 3) << 4)) * 8)) = pk;
}

// ---------------- K1c: Wd -> MFMA bf16 B-frag layout ----------------
__global__ void k_fragWd(const float* __restrict__ Wd) {
    int gid = blockIdx.x * blockDim.x + threadIdx.x;
    int l = gid & 63, tile = gid >> 6;
    int kt = tile & 15, nt = tile >> 4;
    int n = nt * 16 + (l & 15), k0 = kt * 32 + (l >> 4) * 8;
    const float* src = Wd + (size_t)n * H_ + k0;
#pragma unroll
    for (int j = 0; j < 8; j++) g_Wdf[(size_t)gid * 8 + j] = f2bf(src[j]);
}

// ---------------- K2: recurrence — int8 Wh on-CU (R13) + 3 cuts ----------------
// 16 blocks x 16 rows; 512 thr = 8 waves; wave owns ntiles 4w..4w+3.
// vs R13: (1) SW(r) swizzle adds r&8 bit -> epilogue byte-writes ~4-way not 8-way;
// (2) tanh via raw v_exp/v_rcp (no libm fixups); (3) u-term via 4x8-B packed loads
// (R5 layout) instead of 16 scattered 2-B. Same kt 0..6-in-regs / 7..15-in-LDS
// split, i8 h-image dbuf, ONE lgkm-only barrier, hs stores never drained.
__global__ void __launch_bounds__(512) k_rnn(const int* __restrict__ x,
                                             const float* __restrict__ h0,
                                             float* __restrict__ out) {
    __shared__ __align__(16) signed char lds_img[2][16 * 512];        // 16 KB dbuf
    __shared__ __align__(16) signed char lds_W[8 * 4 * 9 * 512];      // 144 KB kt 7..15
    const int tid = threadIdx.x;
    const int w = tid >> 6, l = tid & 63;
    const int hi = l >> 4, lo = l & 15;
    const int r0 = blockIdx.x * 16;
    const int w4 = w * 4;
    const int nb = w * 64 + lo;                 // n = nb + nt*16
    const int swl = SW(lo);                     // A-read swizzle

    // pinned B-frags kt 0..6 (4 nt x 7 kt x 8 B = 56 VGPRs)
    long breg[4][7];
#pragma unroll
    for (int nt = 0; nt < 4; nt++)
#pragma unroll
        for (int kt = 0; kt < 7; kt++)
            breg[nt][kt] = *(const long*)(g_Whq + ((w4 + nt) * 16 + kt) * 512 + l * 8);

    // LDS-resident B-frags kt 7..15 (144 KB; lane-contiguous l*8 -> conflict-free)
#pragma unroll
    for (int nt = 0; nt < 4; nt++)
#pragma unroll
        for (int ktl = 0; ktl < 9; ktl++) {
            long v = *(const long*)(g_Whq + ((w4 + nt) * 16 + 7 + ktl) * 512 + l * 8);
            *(long*)(lds_W + (((w4 + nt) * 9 + ktl) * 512) + l * 8) = v;
        }

    // per-output scales: gs[nt] = s_n / 127
    float gs[4];
#pragma unroll
    for (int nt = 0; nt < 4; nt++) gs[nt] = g_scale[nb + nt * 16] * (1.f / 127.f);

    // stage h0 -> image 0 (f32 -> i8, SW-swizzled, 8-B granular writes)
    {
        const int row = tid >> 5;
        const int c0 = (tid & 31) * 16;
        const float* hp = h0 + (size_t)(r0 + row) * H_ + c0;
        union { unsigned char b[16]; unsigned long long q[2]; } pk;
#pragma unroll
        for (int i = 0; i < 16; i++) {
            int qq = __float2int_rn(fminf(fmaxf(hp[i], -1.f), 1.f) * 127.f);
            pk.b[i] = (unsigned char)(signed char)qq;
        }
        const int sr = SW(row);
        *(unsigned long long*)(lds_img[0] + row * 512 + ((c0)     ^ sr)) = pk.q[0];
        *(unsigned long long*)(lds_img[0] + row * 512 + ((c0 + 8) ^ sr)) = pk.q[1];
    }

    // x for t=0 (thread's 4 batch rows r = hi*4+rg)
    const int xr = r0 + hi * 4;
    int xs0 = x[(xr + 0) * T_], xs1 = x[(xr + 1) * T_],
        xs2 = x[(xr + 2) * T_], xs3 = x[(xr + 3) * T_];

    const int eo0 = (xr + 0) * (T_ * H_) + nb;
    const int eo1 = (xr + 1) * (T_ * H_) + nb;
    const int eo2 = (xr + 2) * (T_ * H_) + nb;
    const int eo3 = (xr + 3) * (T_ * H_) + nb;

    unsigned short* hs = (unsigned short*)out;   // hs bf16 in-place in d_out
    float* hfin = out + (size_t)B_ * T_ * O_;
    __syncthreads();

#pragma unroll 1
    for (int t = 0; t < T_; t++) {
        // u = P2[x[r,t]]: 4 x 8-B packed loads (consumed in epilogue; latency hidden)
        unsigned up[4][2];
        {
            const int pb = (w << 5) + (lo << 1);
            *(uint2*)&up[0][0] = *(const uint2*)(g_P2 + (xs0 << 8) + pb);
            *(uint2*)&up[1][0] = *(const uint2*)(g_P2 + (xs1 << 8) + pb);
            *(uint2*)&up[2][0] = *(const uint2*)(g_P2 + (xs2 << 8) + pb);
            *(uint2*)&up[3][0] = *(const uint2*)(g_P2 + (xs3 << 8) + pb);
        }
        // x prefetch t+1
        {
            const int tn = (t < T_ - 1) ? t + 1 : t;
            xs0 = x[(xr + 0) * T_ + tn]; xs1 = x[(xr + 1) * T_ + tn];
            xs2 = x[(xr + 2) * T_ + tn]; xs3 = x[(xr + 3) * T_ + tn];
        }

        // MFMA: acc_nt(i32) = sum_k qh * qw  (4 indep chains)
        i32x4 acc[4];
#pragma unroll
        for (int nt = 0; nt < 4; nt++) { acc[nt][0] = 0; acc[nt][1] = 0; acc[nt][2] = 0; acc[nt][3] = 0; }
        const signed char* img = lds_img[t & 1];
#pragma unroll
        for (int kt = 0; kt < 7; kt++) {
            long a = *(const long*)(img + lo * 512 + ((kt * 32 + hi * 8) ^ swl));
            acc[0] = __builtin_amdgcn_mfma_i32_16x16x32_i8(a, breg[0][kt], acc[0], 0, 0, 0);
            acc[1] = __builtin_amdgcn_mfma_i32_16x16x32_i8(a, breg[1][kt], acc[1], 0, 0, 0);
            acc[2] = __builtin_amdgcn_mfma_i32_16x16x32_i8(a, breg[2][kt], acc[2], 0, 0, 0);
            acc[3] = __builtin_amdgcn_mfma_i32_16x16x32_i8(a, breg[3][kt], acc[3], 0, 0, 0);
        }
#pragma unroll
        for (int ktl = 0; ktl < 9; ktl++) {
            const int kt = 7 + ktl;
            long a = *(const long*)(img + lo * 512 + ((kt * 32 + hi * 8) ^ swl));
            long b0 = *(const long*)(lds_W + (((w4 + 0) * 9 + ktl) * 512) + l * 8);
            long b1 = *(const long*)(lds_W + (((w4 + 1) * 9 + ktl) * 512) + l * 8);
            long b2 = *(const long*)(lds_W + (((w4 + 2) * 9 + ktl) * 512) + l * 8);
            long b3 = *(const long*)(lds_W + (((w4 + 3) * 9 + ktl) * 512) + l * 8);
            acc[0] = __builtin_amdgcn_mfma_i32_16x16x32_i8(a, b0, acc[0], 0, 0, 0);
            acc[1] = __builtin_amdgcn_mfma_i32_16x16x32_i8(a, b1, acc[1], 0, 0, 0);
            acc[2] = __builtin_amdgcn_mfma_i32_16x16x32_i8(a, b2, acc[2], 0, 0, 0);
            acc[3] = __builtin_amdgcn_mfma_i32_16x16x32_i8(a, b3, acc[3], 0, 0, 0);
        }

        // epilogue: f = acc*s + u; h = tanh_fast(f); hs bf16 (never drained);
        // image[c^1] gets round(h*127) i8 at SW-swizzled col
        signed char* imw = lds_img[(t & 1) ^ 1];
        const int tb = t << 9;
#pragma unroll
        for (int nt = 0; nt < 4; nt++) {
            const int nn = nb + nt * 16;
#pragma unroll
            for (int rg = 0; rg < 4; rg++) {
                const int r = hi * 4 + rg;          // C/D row = (lane>>4)*4 + reg [m89]
                const unsigned uw = up[rg][nt >> 1];
                const float uf = bf2f((nt & 1) ? (unsigned short)(uw >> 16)
                                               : (unsigned short)(uw & 0xffffu));
                float f = (float)acc[nt][rg] * gs[nt] + uf;
                float th = tanh_fast(f);
                const int eo = (rg == 0) ? eo0 : (rg == 1) ? eo1 : (rg == 2) ? eo2 : eo3;
                hs[eo + tb + nt * 16] = f2bf(th);
                int q = __float2int_rn(th * 127.f);
                imw[r * 512 + (nn ^ SW(r))] = (signed char)q;
                if (t == T_ - 1) hfin[(r0 + r) * H_ + nn] = th;
            }
        }

        // single barrier: LDS visibility only (hs stores fly freely)
        __builtin_amdgcn_sched_barrier(0);
        asm volatile("s_waitcnt lgkmcnt(0)" ::: "memory");
        __builtin_amdgcn_s_barrier();
        __builtin_amdgcn_sched_barrier(0);
    }
}

// ---------------- K3: outputs = hs @ Wd^T + bd, in-place over hs slots ----------------
__launch_bounds__(512, 2)
__global__ void k_out(const float* __restrict__ bd, float* out) {
    int tid = threadIdx.x;
    int w = tid >> 6, l = tid & 63;
    int hi = l >> 4, lo = l & 15;
    size_t m0 = (size_t)blockIdx.x * 256 + w * 32;
    const unsigned short* hsb = (const unsigned short*)out;
    float bdv[16];
#pragma unroll
    for (int nt = 0; nt < 16; nt++) bdv[nt] = bd[nt * 16 + lo];
    f32x4 acc[2][16];
#pragma unroll
    for (int m = 0; m < 2; m++)
#pragma unroll
        for (int nt = 0; nt < 16; nt++) { acc[m][nt][0] = 0.f; acc[m][nt][1] = 0.f; acc[m][nt][2] = 0.f; acc[m][nt][3] = 0.f; }
#pragma unroll 2
    for (int kt = 0; kt < 16; kt++) {
        bf16x8 a0 = *(const bf16x8*)(hsb + (m0 + lo) * 512 + kt * 32 + hi * 8);
        bf16x8 a1 = *(const bf16x8*)(hsb + (m0 + 16 + lo) * 512 + kt * 32 + hi * 8);
#pragma unroll
        for (int nt = 0; nt < 16; nt++) {
            bf16x8 bf = *(const bf16x8*)(g_Wdf + (size_t)(nt * 16 + kt) * 512 + l * 8);
            acc[0][nt] = __builtin_amdgcn_mfma_f32_16x16x32_bf16(a0, bf, acc[0][nt], 0, 0, 0);
            acc[1][nt] = __builtin_amdgcn_mfma_f32_16x16x32_bf16(a1, bf, acc[1][nt], 0, 0, 0);
        }
    }
#pragma unroll
    for (int m = 0; m < 2; m++)
#pragma unroll
        for (int nt = 0; nt < 16; nt++)
#pragma unroll
            for (int rg = 0; rg < 4; rg++) {
                size_t row = m0 + m * 16 + hi * 4 + rg;
                out[row * O_ + nt * 16 + lo] = acc[m][nt][rg] + bdv[nt];
            }
}

extern "C" void kernel_launch(void* const* d_in, const int* in_sizes, int n_in,
                              void* d_out, int out_size, void* d_ws, size_t ws_size,
                              hipStream_t stream) {
    const int*   x   = (const int*)d_in[0];
    const float* h0  = (const float*)d_in[1];
    const float* emb = (const float*)d_in[2];
    const float* W   = (const float*)d_in[3];
    const float* b   = (const float*)d_in[4];
    const float* Wd  = (const float*)d_in[5];
    const float* bd  = (const float*)d_in[6];
    float* out = (float*)d_out;

    k_embWx<<<dim3(V_), dim3(256), 0, stream>>>(emb, W, b);
    k_prep8<<<dim3(H_), dim3(64), 0, stream>>>(W);
    k_fragWd<<<dim3(64), dim3(256), 0, stream>>>(Wd);
    k_rnn<<<dim3(16), dim3(512), 0, stream>>>(x, h0, out);
    k_out<<<dim3(1024), dim3(512), 0, stream>>>(bd, out);
}

// Round 15
// 2371.293 us; speedup vs baseline: 3.8928x; 1.1374x over previous
//
#include <hip/hip_runtime.h>

typedef short bf16x8 __attribute__((ext_vector_type(8)));
typedef float f32x4 __attribute__((ext_vector_type(4)));
typedef int i32x4 __attribute__((ext_vector_type(4)));

#define B_ 256
#define T_ 1024
#define H_ 512
#define E_ 256
#define O_ 256
#define V_ 256

// Prepped operands in device globals: graph-safe, rewritten every launch.
__device__ __align__(16) unsigned g_P2[V_ * 256];         // P packed u32 pairs (R5-verified layout)
__device__ __align__(16) signed char    g_Whq[H_ * H_];   // Wh int8, MFMA B-frag layout (256 KB)
__device__ float                        g_scale[H_];      // per-row Wh quant scale
__device__ __align__(16) signed char    g_Wdq[O_ * H_];   // Wd int8, MFMA B-frag layout (128 KB)
__device__ float                        g_sd[O_];         // per-row Wd quant scale

__device__ __forceinline__ unsigned short f2bf(float f) {
    union { float f; unsigned int u; } v; v.f = f;
    unsigned int r = v.u + 0x7fffu + ((v.u >> 16) & 1u);   // RNE
    return (unsigned short)(r >> 16);
}
__device__ __forceinline__ float bf2f(unsigned short s) {
    union { unsigned int u; float f; } v; v.u = ((unsigned int)s) << 16;
    return v.f;
}
// tanh(f) = 1 - 2/(exp2(f*2log2e)+1): raw v_exp/v_rcp (no libm fixup chains)
__device__ __forceinline__ float tanh_fast(float f) {
    float kf = f * 2.885390081777927f;
    float E; asm("v_exp_f32 %0, %1" : "=v"(E) : "v"(kf));
    float d = E + 1.f;
    float r; asm("v_rcp_f32 %0, %1" : "=v"(r) : "v"(d));
    return __builtin_fmaf(-2.f, r, 1.f);
}
#define SW(r_) ((((r_) & 7) << 4) ^ ((r_) & 8))

// ---------------- K1a: P2 = packed(b + emb @ Wx^T) ----------------
__global__ void k_embWx(const float* __restrict__ emb, const float* __restrict__ W,
                        const float* __restrict__ bb) {
    __shared__ float e[E_];
    int v = blockIdx.x;
    e[threadIdx.x] = emb[(size_t)v * E_ + threadIdx.x];
    __syncthreads();
#pragma unroll
    for (int rep = 0; rep < 2; rep++) {
        int n = threadIdx.x + rep * 256;
        const float4* wr4 = (const float4*)(W + (size_t)n * (E_ + H_));
        float s = bb[n];
        for (int k = 0; k < E_ / 4; k++) {
            float4 wv = wr4[k];
            s += e[4*k] * wv.x + e[4*k+1] * wv.y + e[4*k+2] * wv.z + e[4*k+3] * wv.w;
        }
        int w = n >> 6, r6 = n & 63;
        int lo = r6 & 15, nt = r6 >> 4;
        int p = nt >> 1, half = nt & 1;
        ((unsigned short*)g_P2)[(v * 256 + w * 32 + lo * 2 + p) * 2 + half] = f2bf(s);
    }
}

// ---------------- K1b: Wh -> int8 + per-row scale, MFMA i8 B-frag layout ----------------
__global__ void k_prep8(const float* __restrict__ W) {
    const int n = blockIdx.x;
    const int li = threadIdx.x;
    const float* src = W + (size_t)n * (E_ + H_) + E_;   // Wh row n = W[n][256:768]
    float v[8];
    float mx = 0.f;
#pragma unroll
    for (int m = 0; m < 8; m++) { v[m] = src[li * 8 + m]; mx = fmaxf(mx, fabsf(v[m])); }
#pragma unroll
    for (int off = 1; off < 64; off <<= 1)
        mx = fmaxf(mx, __shfl_xor(mx, off));
    const float s = fmaxf(mx, 1e-20f) / 127.f;
    if (li == 0) g_scale[n] = s;
    const float inv = 1.f / s;
    unsigned long long pk = 0;
#pragma unroll
    for (int m = 0; m < 8; m++) {
        int q = __float2int_rn(v[m] * inv);
        q = q > 127 ? 127 : (q < -127 ? -127 : q);
        pk |= ((unsigned long long)(unsigned char)(signed char)q) << (8 * m);
    }
    *(unsigned long long*)(g_Whq + (((size_t)(n >> 4) * 16 + (li >> 2)) * 512)
                           + (((n & 15) + ((li & 3) << 4)) * 8)) = pk;
}

// ---------------- K1c: Wd -> int8 + per-row scale, MFMA i8 B-frag layout ----------------
__global__ void k_prepWd8(const float* __restrict__ Wd) {
    const int n = blockIdx.x;
    const int li = threadIdx.x;
    const float* src = Wd + (size_t)n * H_;
    float v[8];
    float mx = 0.f;
#pragma unroll
    for (int m = 0; m < 8; m++) { v[m] = src[li * 8 + m]; mx = fmaxf(mx, fabsf(v[m])); }
#pragma unroll
    for (int off = 1; off < 64; off <<= 1)
        mx = fmaxf(mx, __shfl_xor(mx, off));
    const float s = fmaxf(mx, 1e-20f) / 127.f;
    if (li == 0) g_sd[n] = s;
    const float inv = 1.f / s;
    unsigned long long pk = 0;
#pragma unroll
    for (int m = 0; m < 8; m++) {
        int q = __float2int_rn(v[m] * inv);
        q = q > 127 ? 127 : (q < -127 ? -127 : q);
        pk |= ((unsigned long long)(unsigned char)(signed char)q) << (8 * m);
    }
    *(unsigned long long*)(g_Wdq + (((size_t)(n >> 4) * 16 + (li >> 2)) * 512)
                           + (((n & 15) + ((li & 3) << 4)) * 8)) = pk;
}

// ---------------- K2: recurrence — int8 on-CU, i8 hs output ----------------
// 16 blocks x 16 rows; 512 thr = 8 waves; wave owns ntiles 4w..4w+3.
// vs R14: (1) hs stored as i8 (reuse the image q bytes) at 1024-B row stride —
// deletes all f2bf chains (~48 VALU/thread-step) and halves hs bytes; k_out reads
// it as i8 A-frags in the exact bytes it later overwrites (per-wave read-then-
// write, alias-safe). (2) breg kt 0..8 (72 VGPRs, demand ~120 < 128 grant), LDS
// kt 9..15 (112 KB) -> B-LDS reads 36->28. R14 correction: 4.19M bank conflicts
// = only ~64 cy/step/SIMD — NOT a bottleneck; epilogue VALU is.
__global__ void __launch_bounds__(512) k_rnn(const int* __restrict__ x,
                                             const float* __restrict__ h0,
                                             float* __restrict__ out) {
    __shared__ __align__(16) signed char lds_img[2][16 * 512];        // 16 KB dbuf
    __shared__ __align__(16) signed char lds_W[8 * 4 * 7 * 512];      // 112 KB kt 9..15
    const int tid = threadIdx.x;
    const int w = tid >> 6, l = tid & 63;
    const int hi = l >> 4, lo = l & 15;
    const int r0 = blockIdx.x * 16;
    const int w4 = w * 4;
    const int nb = w * 64 + lo;                 // n = nb + nt*16
    const int swl = SW(lo);                     // A-read swizzle

    // pinned B-frags kt 0..8 (4 nt x 9 kt x 8 B = 72 VGPRs)
    long breg[4][9];
#pragma unroll
    for (int nt = 0; nt < 4; nt++)
#pragma unroll
        for (int kt = 0; kt < 9; kt++)
            breg[nt][kt] = *(const long*)(g_Whq + ((w4 + nt) * 16 + kt) * 512 + l * 8);

    // LDS-resident B-frags kt 9..15
#pragma unroll
    for (int nt = 0; nt < 4; nt++)
#pragma unroll
        for (int ktl = 0; ktl < 7; ktl++) {
            long v = *(const long*)(g_Whq + ((w4 + nt) * 16 + 9 + ktl) * 512 + l * 8);
            *(long*)(lds_W + (((w4 + nt) * 7 + ktl) * 512) + l * 8) = v;
        }

    // per-output scales: gs[nt] = s_n / 127
    float gs[4];
#pragma unroll
    for (int nt = 0; nt < 4; nt++) gs[nt] = g_scale[nb + nt * 16] * (1.f / 127.f);

    // stage h0 -> image 0 (f32 -> i8, SW-swizzled)
    {
        const int row = tid >> 5;
        const int c0 = (tid & 31) * 16;
        const float* hp = h0 + (size_t)(r0 + row) * H_ + c0;
        union { unsigned char b[16]; unsigned long long q[2]; } pk;
#pragma unroll
        for (int i = 0; i < 16; i++) {
            int qq = __float2int_rn(fminf(fmaxf(hp[i], -1.f), 1.f) * 127.f);
            pk.b[i] = (unsigned char)(signed char)qq;
        }
        const int sr = SW(row);
        *(unsigned long long*)(lds_img[0] + row * 512 + ((c0)     ^ sr)) = pk.q[0];
        *(unsigned long long*)(lds_img[0] + row * 512 + ((c0 + 8) ^ sr)) = pk.q[1];
    }

    // x for t=0 (thread's 4 batch rows r = hi*4+rg)
    const int xr = r0 + hi * 4;
    int xs0 = x[(xr + 0) * T_], xs1 = x[(xr + 1) * T_],
        xs2 = x[(xr + 2) * T_], xs3 = x[(xr + 3) * T_];

    // hs-i8 byte offsets: row (b*T+t) at byte (b*T+t)*1024 (stride 1024, n < 512)
    const int eo0 = (xr + 0) * (T_ * 1024) + nb;
    const int eo1 = (xr + 1) * (T_ * 1024) + nb;
    const int eo2 = (xr + 2) * (T_ * 1024) + nb;
    const int eo3 = (xr + 3) * (T_ * 1024) + nb;

    unsigned char* hsb = (unsigned char*)out;    // hs i8 in-place in d_out
    float* hfin = out + (size_t)B_ * T_ * O_;
    __syncthreads();

#pragma unroll 1
    for (int t = 0; t < T_; t++) {
        // u = P2[x[r,t]]: 4 x 8-B packed loads (consumed in epilogue)
        unsigned up[4][2];
        {
            const int pb = (w << 5) + (lo << 1);
            *(uint2*)&up[0][0] = *(const uint2*)(g_P2 + (xs0 << 8) + pb);
            *(uint2*)&up[1][0] = *(const uint2*)(g_P2 + (xs1 << 8) + pb);
            *(uint2*)&up[2][0] = *(const uint2*)(g_P2 + (xs2 << 8) + pb);
            *(uint2*)&up[3][0] = *(const uint2*)(g_P2 + (xs3 << 8) + pb);
        }
        // x prefetch t+1
        {
            const int tn = (t < T_ - 1) ? t + 1 : t;
            xs0 = x[(xr + 0) * T_ + tn]; xs1 = x[(xr + 1) * T_ + tn];
            xs2 = x[(xr + 2) * T_ + tn]; xs3 = x[(xr + 3) * T_ + tn];
        }

        // MFMA: acc_nt(i32) = sum_k qh * qw  (4 indep chains)
        i32x4 acc[4];
#pragma unroll
        for (int nt = 0; nt < 4; nt++) { acc[nt][0] = 0; acc[nt][1] = 0; acc[nt][2] = 0; acc[nt][3] = 0; }
        const signed char* img = lds_img[t & 1];
#pragma unroll
        for (int kt = 0; kt < 9; kt++) {
            long a = *(const long*)(img + lo * 512 + ((kt * 32 + hi * 8) ^ swl));
            acc[0] = __builtin_amdgcn_mfma_i32_16x16x32_i8(a, breg[0][kt], acc[0], 0, 0, 0);
            acc[1] = __builtin_amdgcn_mfma_i32_16x16x32_i8(a, breg[1][kt], acc[1], 0, 0, 0);
            acc[2] = __builtin_amdgcn_mfma_i32_16x16x32_i8(a, breg[2][kt], acc[2], 0, 0, 0);
            acc[3] = __builtin_amdgcn_mfma_i32_16x16x32_i8(a, breg[3][kt], acc[3], 0, 0, 0);
        }
#pragma unroll
        for (int ktl = 0; ktl < 7; ktl++) {
            const int kt = 9 + ktl;
            long a = *(const long*)(img + lo * 512 + ((kt * 32 + hi * 8) ^ swl));
            long b0 = *(const long*)(lds_W + (((w4 + 0) * 7 + ktl) * 512) + l * 8);
            long b1 = *(const long*)(lds_W + (((w4 + 1) * 7 + ktl) * 512) + l * 8);
            long b2 = *(const long*)(lds_W + (((w4 + 2) * 7 + ktl) * 512) + l * 8);
            long b3 = *(const long*)(lds_W + (((w4 + 3) * 7 + ktl) * 512) + l * 8);
            acc[0] = __builtin_amdgcn_mfma_i32_16x16x32_i8(a, b0, acc[0], 0, 0, 0);
            acc[1] = __builtin_amdgcn_mfma_i32_16x16x32_i8(a, b1, acc[1], 0, 0, 0);
            acc[2] = __builtin_amdgcn_mfma_i32_16x16x32_i8(a, b2, acc[2], 0, 0, 0);
            acc[3] = __builtin_amdgcn_mfma_i32_16x16x32_i8(a, b3, acc[3], 0, 0, 0);
        }

        // epilogue: f = acc*s + u; h = tanh_fast(f); q = round(h*127);
        // q -> hs-i8 global byte (never drained) + image[c^1] (SW-swizzled)
        signed char* imw = lds_img[(t & 1) ^ 1];
        const int tb = t << 10;                  // t*1024 bytes
#pragma unroll
        for (int nt = 0; nt < 4; nt++) {
            const int nn = nb + nt * 16;
#pragma unroll
            for (int rg = 0; rg < 4; rg++) {
                const int r = hi * 4 + rg;       // C/D row = (lane>>4)*4 + reg [m89]
                const unsigned uw = up[rg][nt >> 1];
                const float uf = bf2f((nt & 1) ? (unsigned short)(uw >> 16)
                                               : (unsigned short)(uw & 0xffffu));
                float f = (float)acc[nt][rg] * gs[nt] + uf;
                float th = tanh_fast(f);
                int q = __float2int_rn(th * 127.f);
                const int eo = (rg == 0) ? eo0 : (rg == 1) ? eo1 : (rg == 2) ? eo2 : eo3;
                hsb[eo + tb + nt * 16] = (unsigned char)(signed char)q;
                imw[r * 512 + (nn ^ SW(r))] = (signed char)q;
                if (t == T_ - 1) hfin[(r0 + r) * H_ + nn] = th;
            }
        }

        // single barrier: LDS visibility only (global stores fly freely)
        __builtin_amdgcn_sched_barrier(0);
        asm volatile("s_waitcnt lgkmcnt(0)" ::: "memory");
        __builtin_amdgcn_s_barrier();
        __builtin_amdgcn_sched_barrier(0);
    }
}

// ---------------- K3: outputs = (hs-i8) @ (Wd-i8)^T * scales + bd, in-place ----------------
// 1024 blocks x 256 (b,t)-rows; wave w: 32 rows. Reads i8 hs (first 512 B of each
// 1024-B row slot) from the exact bytes it later overwrites with f32 outputs;
// per-wave all reads precede all writes. i8 MFMA = 2x rate, half A-fetch of R14.
__launch_bounds__(512, 2)
__global__ void k_out(const float* __restrict__ bd, float* out) {
    int tid = threadIdx.x;
    int w = tid >> 6, l = tid & 63;
    int hi = l >> 4, lo = l & 15;
    size_t m0 = (size_t)blockIdx.x * 256 + w * 32;
    const unsigned char* hsb = (const unsigned char*)out;
    float bdv[16], sdl[16];
#pragma unroll
    for (int nt = 0; nt < 16; nt++) {
        bdv[nt] = bd[nt * 16 + lo];
        sdl[nt] = g_sd[nt * 16 + lo] * (1.f / 127.f);
    }
    i32x4 acc[2][16];
#pragma unroll
    for (int m = 0; m < 2; m++)
#pragma unroll
        for (int nt = 0; nt < 16; nt++) { acc[m][nt][0] = 0; acc[m][nt][1] = 0; acc[m][nt][2] = 0; acc[m][nt][3] = 0; }
#pragma unroll 2
    for (int kt = 0; kt < 16; kt++) {
        long a0 = *(const long*)(hsb + (m0 + lo) * 1024 + kt * 32 + hi * 8);
        long a1 = *(const long*)(hsb + (m0 + 16 + lo) * 1024 + kt * 32 + hi * 8);
#pragma unroll
        for (int nt = 0; nt < 16; nt++) {
            long bf = *(const long*)(g_Wdq + (nt * 16 + kt) * 512 + l * 8);
            acc[0][nt] = __builtin_amdgcn_mfma_i32_16x16x32_i8(a0, bf, acc[0][nt], 0, 0, 0);
            acc[1][nt] = __builtin_amdgcn_mfma_i32_16x16x32_i8(a1, bf, acc[1][nt], 0, 0, 0);
        }
    }
#pragma unroll
    for (int m = 0; m < 2; m++)
#pragma unroll
        for (int nt = 0; nt < 16; nt++)
#pragma unroll
            for (int rg = 0; rg < 4; rg++) {
                size_t row = m0 + m * 16 + hi * 4 + rg;
                out[row * O_ + nt * 16 + lo] = (float)acc[m][nt][rg] * sdl[nt] + bdv[nt];
            }
}

extern "C" void kernel_launch(void* const* d_in, const int* in_sizes, int n_in,
                              void* d_out, int out_size, void* d_ws, size_t ws_size,
                              hipStream_t stream) {
    const int*   x   = (const int*)d_in[0];
    const float* h0  = (const float*)d_in[1];
    const float* emb = (const float*)d_in[2];
    const float* W   = (const float*)d_in[3];
    const float* b   = (const float*)d_in[4];
    const float* Wd  = (const float*)d_in[5];
    const float* bd  = (const float*)d_in[6];
    float* out = (float*)d_out;

    k_embWx<<<dim3(V_), dim3(256), 0, stream>>>(emb, W, b);
    k_prep8<<<dim3(H_), dim3(64), 0, stream>>>(W);
    k_prepWd8<<<dim3(O_), dim3(64), 0, stream>>>(Wd);
    k_rnn<<<dim3(16), dim3(512), 0, stream>>>(x, h0, out);
    k_out<<<dim3(1024), dim3(512), 0, stream>>>(bd, out);
}

// Round 16
// 1820.040 us; speedup vs baseline: 5.0718x; 1.3029x over previous
//
#include <hip/hip_runtime.h>

typedef float f32x4 __attribute__((ext_vector_type(4)));
typedef int i32x4 __attribute__((ext_vector_type(4)));

#define B_ 256
#define T_ 1024
#define H_ 512
#define E_ 256
#define O_ 256
#define V_ 256

// Prepped operands in device globals: graph-safe, rewritten every launch.
__device__ __align__(16) unsigned g_P2[V_ * 256];         // P packed u32 pairs (R5 layout)
__device__ __align__(16) signed char    g_Whq[H_ * H_];   // Wh int8, K=64 frag layout (256 KB)
__device__ float                        g_scale[H_];      // per-row Wh quant scale
__device__ __align__(16) signed char    g_Wdq[O_ * H_];   // Wd int8, K=64 frag layout (128 KB)
__device__ float                        g_sd[O_];         // per-row Wd quant scale

__device__ __forceinline__ unsigned short f2bf(float f) {
    union { float f; unsigned int u; } v; v.f = f;
    unsigned int r = v.u + 0x7fffu + ((v.u >> 16) & 1u);   // RNE
    return (unsigned short)(r >> 16);
}
__device__ __forceinline__ float bf2f(unsigned short s) {
    union { unsigned int u; float f; } v; v.u = ((unsigned int)s) << 16;
    return v.f;
}
// 16-B-aligned row swizzle (b128-safe; conflicts proven negligible in R14 anyway)
#define SW16(r_) (((r_) & 15) << 4)

// ---------------- K1a: P2 = packed(b + emb @ Wx^T) ----------------
__global__ void k_embWx(const float* __restrict__ emb, const float* __restrict__ W,
                        const float* __restrict__ bb) {
    __shared__ float e[E_];
    int v = blockIdx.x;
    e[threadIdx.x] = emb[(size_t)v * E_ + threadIdx.x];
    __syncthreads();
#pragma unroll
    for (int rep = 0; rep < 2; rep++) {
        int n = threadIdx.x + rep * 256;
        const float4* wr4 = (const float4*)(W + (size_t)n * (E_ + H_));
        float s = bb[n];
        for (int k = 0; k < E_ / 4; k++) {
            float4 wv = wr4[k];
            s += e[4*k] * wv.x + e[4*k+1] * wv.y + e[4*k+2] * wv.z + e[4*k+3] * wv.w;
        }
        int w = n >> 6, r6 = n & 63;
        int lo = r6 & 15, nt = r6 >> 4;
        int p = nt >> 1, half = nt & 1;
        ((unsigned short*)g_P2)[(v * 256 + w * 32 + lo * 2 + p) * 2 + half] = f2bf(s);
    }
}

// ---------------- K1b: Wh -> int8, K=64 frag layout ----------------
// Tile (ntile, ktt): 1024 B; lane l holds 16 bytes at l*16; byte j of lane l =
// W[n = ntile*16 + (l&15)][k = ktt*64 + (l>>4)*16 + j]. A-image reads use the
// SAME k-order -> dot product correct for ANY hw (lane,elem)->k mapping.
__global__ void k_prep8(const float* __restrict__ W) {
    const int n = blockIdx.x;
    const int li = threadIdx.x;                  // covers k = li*8 .. li*8+7
    const float* src = W + (size_t)n * (E_ + H_) + E_;   // Wh row n = W[n][256:768]
    float v[8];
    float mx = 0.f;
#pragma unroll
    for (int m = 0; m < 8; m++) { v[m] = src[li * 8 + m]; mx = fmaxf(mx, fabsf(v[m])); }
#pragma unroll
    for (int off = 1; off < 64; off <<= 1)
        mx = fmaxf(mx, __shfl_xor(mx, off));
    const float s = fmaxf(mx, 1e-20f) / 127.f;
    if (li == 0) g_scale[n] = s;
    const float inv = 1.f / s;
    unsigned long long pk = 0;
#pragma unroll
    for (int m = 0; m < 8; m++) {
        int q = __float2int_rn(v[m] * inv);
        q = q > 127 ? 127 : (q < -127 ? -127 : q);
        pk |= ((unsigned long long)(unsigned char)(signed char)q) << (8 * m);
    }
    const int ktt = li >> 3;                     // k/64
    const int hig = (li >> 1) & 3;               // (k&63)/16
    const int jh = li & 1;                       // byte-half within the 16
    *(unsigned long long*)(g_Whq + (((size_t)(n >> 4) * 8 + ktt) * 1024)
                           + ((n & 15) + (hig << 4)) * 16 + jh * 8) = pk;
}

// ---------------- K1c: Wd -> int8, K=64 frag layout ----------------
__global__ void k_prepWd8(const float* __restrict__ Wd) {
    const int n = blockIdx.x;
    const int li = threadIdx.x;
    const float* src = Wd + (size_t)n * H_;
    float v[8];
    float mx = 0.f;
#pragma unroll
    for (int m = 0; m < 8; m++) { v[m] = src[li * 8 + m]; mx = fmaxf(mx, fabsf(v[m])); }
#pragma unroll
    for (int off = 1; off < 64; off <<= 1)
        mx = fmaxf(mx, __shfl_xor(mx, off));
    const float s = fmaxf(mx, 1e-20f) / 127.f;
    if (li == 0) g_sd[n] = s;
    const float inv = 1.f / s;
    unsigned long long pk = 0;
#pragma unroll
    for (int m = 0; m < 8; m++) {
        int q = __float2int_rn(v[m] * inv);
        q = q > 127 ? 127 : (q < -127 ? -127 : q);
        pk |= ((unsigned long long)(unsigned char)(signed char)q) << (8 * m);
    }
    const int ktt = li >> 3;
    const int hig = (li >> 1) & 3;
    const int jh = li & 1;
    *(unsigned long long*)(g_Wdq + (((size_t)(n >> 4) * 8 + ktt) * 1024)
                           + ((n & 15) + (hig << 4)) * 16 + jh * 8) = pk;
}

// ---------------- K2: recurrence — K=64 i8 MFMA, on-CU Wh, coalesced hs writer ----------------
// 16 blocks x 16 rows; 512 thr = 8 waves; wave owns ntiles 4w..4w+3.
// vs R15: (1) mfma_i32_16x16x64_i8: MFMA 64->32/wave, acc chains 16->8 deep,
// LDS reads 44->24 (b128); (2) hs written COALESCED by all threads from the
// image at top of next step (1 b128 + 1 dwordx4) instead of 16 scattered byte
// stores + eo addressing in the epilogue; (3) q = rndne(fma(-254,rcp(E+1),127)).
// Wh: ktt 0..3 in 64 VGPRs (demand ~108 < 128 grant, slack per R2 lesson),
// ktt 4..7 in 128 KB LDS; images 2x8 KB; LDS = 144 KB. ONE lgkm-only barrier.
__global__ void __launch_bounds__(512) k_rnn(const int* __restrict__ x,
                                             const float* __restrict__ h0,
                                             float* __restrict__ out) {
    __shared__ __align__(16) signed char lds_img[2][16 * 512];    // 16 KB dbuf
    __shared__ __align__(16) signed char lds_W[128 * 1024];       // 128 KB ktt 4..7
    const int tid = threadIdx.x;
    const int w = tid >> 6, l = tid & 63;
    const int hi = l >> 4, lo = l & 15;
    const int r0 = blockIdx.x * 16;
    const int w4 = w * 4;
    const int nb = w * 64 + lo;                 // n = nb + nt*16
    const int swl = SW16(lo);                   // A-read swizzle

    // pinned B-frags ktt 0..3 (4 nt x 4 ktt x 16 B = 64 VGPRs)
    i32x4 breg[4][4];
#pragma unroll
    for (int nt = 0; nt < 4; nt++)
#pragma unroll
        for (int kt = 0; kt < 4; kt++)
            breg[nt][kt] = *(const i32x4*)(g_Whq + ((w4 + nt) * 8 + kt) * 1024 + l * 16);

    // LDS-resident B-frags ktt 4..7 (32 ntiles x 4 ktt x 1 KB = 128 KB)
#pragma unroll
    for (int nt = 0; nt < 4; nt++)
#pragma unroll
        for (int kk = 0; kk < 4; kk++) {
            i32x4 v = *(const i32x4*)(g_Whq + ((w4 + nt) * 8 + 4 + kk) * 1024 + l * 16);
            *(i32x4*)(lds_W + ((w4 + nt) * 4 + kk) * 1024 + l * 16) = v;
        }

    // per-output scales: gs[nt] = s_n / 127
    float gs[4];
#pragma unroll
    for (int nt = 0; nt < 4; nt++) gs[nt] = g_scale[nb + nt * 16] * (1.f / 127.f);

    // stage h0 -> image 0 (f32 -> i8, SW16-swizzled, one uint4/thread)
    {
        const int row = tid >> 5;
        const int c0 = (tid & 31) * 16;
        const float* hp = h0 + (size_t)(r0 + row) * H_ + c0;
        union { unsigned char b[16]; uint4 v; } pk;
#pragma unroll
        for (int i = 0; i < 16; i++) {
            int qq = __float2int_rn(fminf(fmaxf(hp[i], -1.f), 1.f) * 127.f);
            pk.b[i] = (unsigned char)(signed char)qq;
        }
        *(uint4*)(lds_img[0] + row * 512 + (c0 ^ SW16(row))) = pk.v;
    }

    // x for t=0 (thread's 4 batch rows r = hi*4+rg)
    const int xr = r0 + hi * 4;
    int xs0 = x[(xr + 0) * T_], xs1 = x[(xr + 1) * T_],
        xs2 = x[(xr + 2) * T_], xs3 = x[(xr + 3) * T_];

    unsigned char* hsb = (unsigned char*)out;    // hs i8 in-place (1024-B row stride)
    float* hfin = out + (size_t)B_ * T_ * O_;
    __syncthreads();

#pragma unroll 1
    for (int t = 0; t < T_; t++) {
        const signed char* img = lds_img[t & 1];

        // coalesced hs write of h_{t-1} from the fresh image (read covered by the
        // end-of-step lgkmcnt(0); global store never drained)
        if (t) {
            const int row = tid >> 5;
            const int cb = (tid & 31) * 16;
            uint4 d = *(const uint4*)(img + row * 512 + (cb ^ SW16(row)));
            *(uint4*)(hsb + (size_t)(r0 + row) * (T_ * 1024) + (size_t)(t - 1) * 1024 + cb) = d;
        }

        // u = P2[x[r,t]]: 4 x 8-B packed loads (consumed in epilogue)
        unsigned up[4][2];
        {
            const int pb = (w << 5) + (lo << 1);
            *(uint2*)&up[0][0] = *(const uint2*)(g_P2 + (xs0 << 8) + pb);
            *(uint2*)&up[1][0] = *(const uint2*)(g_P2 + (xs1 << 8) + pb);
            *(uint2*)&up[2][0] = *(const uint2*)(g_P2 + (xs2 << 8) + pb);
            *(uint2*)&up[3][0] = *(const uint2*)(g_P2 + (xs3 << 8) + pb);
        }
        // x prefetch t+1
        {
            const int tn = (t < T_ - 1) ? t + 1 : t;
            xs0 = x[(xr + 0) * T_ + tn]; xs1 = x[(xr + 1) * T_ + tn];
            xs2 = x[(xr + 2) * T_ + tn]; xs3 = x[(xr + 3) * T_ + tn];
        }

        // MFMA K=64: 32 per wave (8 ktt x 4 nt), 8-deep chains
        i32x4 acc[4];
#pragma unroll
        for (int nt = 0; nt < 4; nt++) { acc[nt][0] = 0; acc[nt][1] = 0; acc[nt][2] = 0; acc[nt][3] = 0; }
#pragma unroll
        for (int kt = 0; kt < 4; kt++) {
            i32x4 a = *(const i32x4*)(img + lo * 512 + ((kt * 64 + hi * 16) ^ swl));
            acc[0] = __builtin_amdgcn_mfma_i32_16x16x64_i8(a, breg[0][kt], acc[0], 0, 0, 0);
            acc[1] = __builtin_amdgcn_mfma_i32_16x16x64_i8(a, breg[1][kt], acc[1], 0, 0, 0);
            acc[2] = __builtin_amdgcn_mfma_i32_16x16x64_i8(a, breg[2][kt], acc[2], 0, 0, 0);
            acc[3] = __builtin_amdgcn_mfma_i32_16x16x64_i8(a, breg[3][kt], acc[3], 0, 0, 0);
        }
#pragma unroll
        for (int kk = 0; kk < 4; kk++) {
            i32x4 a = *(const i32x4*)(img + lo * 512 + (((4 + kk) * 64 + hi * 16) ^ swl));
            i32x4 b0 = *(const i32x4*)(lds_W + ((w4 + 0) * 4 + kk) * 1024 + l * 16);
            i32x4 b1 = *(const i32x4*)(lds_W + ((w4 + 1) * 4 + kk) * 1024 + l * 16);
            i32x4 b2 = *(const i32x4*)(lds_W + ((w4 + 2) * 4 + kk) * 1024 + l * 16);
            i32x4 b3 = *(const i32x4*)(lds_W + ((w4 + 3) * 4 + kk) * 1024 + l * 16);
            acc[0] = __builtin_amdgcn_mfma_i32_16x16x64_i8(a, b0, acc[0], 0, 0, 0);
            acc[1] = __builtin_amdgcn_mfma_i32_16x16x64_i8(a, b1, acc[1], 0, 0, 0);
            acc[2] = __builtin_amdgcn_mfma_i32_16x16x64_i8(a, b2, acc[2], 0, 0, 0);
            acc[3] = __builtin_amdgcn_mfma_i32_16x16x64_i8(a, b3, acc[3], 0, 0, 0);
        }

        // epilogue: f = acc*gs + u; q = rndne(127 - 254/(exp2(2log2e*f)+1));
        // q -> image[c^1] only (hs handled by the coalesced writer next step)
        signed char* imw = lds_img[(t & 1) ^ 1];
#pragma unroll
        for (int nt = 0; nt < 4; nt++) {
            const int nn = nb + nt * 16;
#pragma unroll
            for (int rg = 0; rg < 4; rg++) {
                const int r = hi * 4 + rg;       // C/D row = (lane>>4)*4 + reg [m89]
                const unsigned uw = up[rg][nt >> 1];
                const float uf = bf2f((nt & 1) ? (unsigned short)(uw >> 16)
                                               : (unsigned short)(uw & 0xffffu));
                float f = __builtin_fmaf((float)acc[nt][rg], gs[nt], uf);
                float kf = f * 2.885390081777927f;
                float E; asm("v_exp_f32 %0, %1" : "=v"(E) : "v"(kf));
                float d1 = E + 1.f;
                float r1; asm("v_rcp_f32 %0, %1" : "=v"(r1) : "v"(d1));
                float qf = __builtin_fmaf(-254.f, r1, 127.f);   // = 127*tanh(f)
                int q = __float2int_rn(qf);
                imw[r * 512 + (nn ^ SW16(r))] = (signed char)q;
                if (t == T_ - 1) hfin[(r0 + r) * H_ + nn] = qf * (1.f / 127.f);
            }
        }

        // single barrier: LDS visibility only (global stores fly freely)
        __builtin_amdgcn_sched_barrier(0);
        asm volatile("s_waitcnt lgkmcnt(0)" ::: "memory");
        __builtin_amdgcn_s_barrier();
        __builtin_amdgcn_sched_barrier(0);
    }

    // tail: hs[:, T-1] coalesced from image[0] (step T-1 wrote img[(1023&1)^1]=img[0])
    {
        const int row = tid >> 5;
        const int cb = (tid & 31) * 16;
        uint4 d = *(const uint4*)(lds_img[0] + row * 512 + (cb ^ SW16(row)));
        *(uint4*)(hsb + (size_t)(r0 + row) * (T_ * 1024) + (size_t)(T_ - 1) * 1024 + cb) = d;
    }
}

// ---------------- K3: outputs = (hs-i8) @ (Wd-i8)^T * scales + bd, in-place ----------------
// 1024 blocks x 256 (b,t)-rows; wave w: 32 rows. Reads i8 hs (first 512 B of each
// 1024-B row slot) from the exact bytes it later overwrites; per-wave reads
// precede writes. K=64 i8 MFMA: 256 MFMA/wave (was 512).
__launch_bounds__(512, 2)
__global__ void k_out(const float* __restrict__ bd, float* out) {
    int tid = threadIdx.x;
    int w = tid >> 6, l = tid & 63;
    int hi = l >> 4, lo = l & 15;
    size_t m0 = (size_t)blockIdx.x * 256 + w * 32;
    const unsigned char* hsb = (const unsigned char*)out;
    float bdv[16], sdl[16];
#pragma unroll
    for (int nt = 0; nt < 16; nt++) {
        bdv[nt] = bd[nt * 16 + lo];
        sdl[nt] = g_sd[nt * 16 + lo] * (1.f / 127.f);
    }
    i32x4 acc[2][16];
#pragma unroll
    for (int m = 0; m < 2; m++)
#pragma unroll
        for (int nt = 0; nt < 16; nt++) { acc[m][nt][0] = 0; acc[m][nt][1] = 0; acc[m][nt][2] = 0; acc[m][nt][3] = 0; }
#pragma unroll 2
    for (int kt = 0; kt < 8; kt++) {
        i32x4 a0 = *(const i32x4*)(hsb + (m0 + lo) * 1024 + kt * 64 + hi * 16);
        i32x4 a1 = *(const i32x4*)(hsb + (m0 + 16 + lo) * 1024 + kt * 64 + hi * 16);
#pragma unroll
        for (int nt = 0; nt < 16; nt++) {
            i32x4 bf = *(const i32x4*)(g_Wdq + (nt * 8 + kt) * 1024 + l * 16);
            acc[0][nt] = __builtin_amdgcn_mfma_i32_16x16x64_i8(a0, bf, acc[0][nt], 0, 0, 0);
            acc[1][nt] = __builtin_amdgcn_mfma_i32_16x16x64_i8(a1, bf, acc[1][nt], 0, 0, 0);
        }
    }
#pragma unroll
    for (int m = 0; m < 2; m++)
#pragma unroll
        for (int nt = 0; nt < 16; nt++)
#pragma unroll
            for (int rg = 0; rg < 4; rg++) {
                size_t row = m0 + m * 16 + hi * 4 + rg;
                out[row * O_ + nt * 16 + lo] = (float)acc[m][nt][rg] * sdl[nt] + bdv[nt];
            }
}

extern "C" void kernel_launch(void* const* d_in, const int* in_sizes, int n_in,
                              void* d_out, int out_size, void* d_ws, size_t ws_size,
                              hipStream_t stream) {
    const int*   x   = (const int*)d_in[0];
    const float* h0  = (const float*)d_in[1];
    const float* emb = (const float*)d_in[2];
    const float* W   = (const float*)d_in[3];
    const float* b   = (const float*)d_in[4];
    const float* Wd  = (const float*)d_in[5];
    const float* bd  = (const float*)d_in[6];
    float* out = (float*)d_out;

    k_embWx<<<dim3(V_), dim3(256), 0, stream>>>(emb, W, b);
    k_prep8<<<dim3(H_), dim3(64), 0, stream>>>(W);
    k_prepWd8<<<dim3(O_), dim3(64), 0, stream>>>(Wd);
    k_rnn<<<dim3(16), dim3(512), 0, stream>>>(x, h0, out);
    k_out<<<dim3(1024), dim3(512), 0, stream>>>(bd, out);
}